// Round 7
// baseline (560.618 us; speedup 1.0000x reference)
//
#include <hip/hip_runtime.h>
#include <hip/hip_fp16.h>
#include <math.h>

#define NN 200000
#define NE 500000
#define FF 166
#define HH 128
#define CC 2
#define TT 49
#define GG 498            // 3*FF
#define PADN 203136
#define MAXTILES 6400
#define KP 84             // k-pairs (166 -> 84 half2, padded)
#define KPAD 192          // K padded to 6*32 for MFMA
#define SCB 512           // scan elements per block
#define SNB 391           // ceil(NN/512)
#define HB 782            // ceil(NN/256) histogram blocks

typedef _Float16 half2v __attribute__((ext_vector_type(2)));
typedef _Float16 f16x8 __attribute__((ext_vector_type(8)));
typedef float f32x4 __attribute__((ext_vector_type(4)));

static __device__ __forceinline__ float fdot2f(half2v a, half2v b, float c) {
#if __has_builtin(__builtin_amdgcn_fdot2)
    return __builtin_amdgcn_fdot2(a, b, c, false);
#else
    return c + (float)a.x * (float)b.x + (float)a.y * (float)b.y;
#endif
}

// ---------------- prep: pack GRU weights as [m][kp][512] half2 (k-pairs), fp32 projT ----------------
__global__ void prep_pack(const float* __restrict__ wih, const float* __restrict__ whh,
                          const float* __restrict__ projw,
                          _Float16* __restrict__ wkp, float* __restrict__ projwT) {
    int idx = blockIdx.x * 256 + threadIdx.x;
    const int A = 2 * KP * 512; // 86016 half2 slots
    if (idx < A) {
        int m = idx / (KP * 512);
        int r = idx - m * (KP * 512);
        int kp = r >> 9, c = r & 511;
        const float* Wm = m ? whh : wih;
        float x0 = 0.0f, x1 = 0.0f;
        if (c < GG) {
            int k0 = 2 * kp, k1 = 2 * kp + 1;
            if (k0 < FF) x0 = Wm[c * FF + k0];
            if (k1 < FF) x1 = Wm[c * FF + k1];
        }
        wkp[2 * idx]     = (_Float16)x0;
        wkp[2 * idx + 1] = (_Float16)x1;
    } else if (idx < A + FF * HH) {
        int q = idx - A;
        int k = q >> 7, h = q & 127;
        projwT[q] = projw[h * FF + k];
    }
}

// ---------------- x -> fp16, padded [NN][192] (half2 slots [NN][96]) ----------------
__global__ __launch_bounds__(256) void x_to_h(const float* __restrict__ x, half2v* __restrict__ x2) {
    int idx = blockIdx.x * 256 + threadIdx.x;
    if (idx >= NN * 96) return;
    int row = idx / 96, cp = idx - row * 96;
    int c0 = cp * 2;
    float v0 = (c0 < FF) ? x[(size_t)row * FF + c0] : 0.0f;
    float v1 = (c0 + 1 < FF) ? x[(size_t)row * FF + c0 + 1] : 0.0f;
    half2v h;
    h[0] = (_Float16)v0;
    h[1] = (_Float16)v1;
    x2[idx] = h;
}

// ---------------- CSR build ----------------
__global__ void count_indeg(const int* __restrict__ dst, int* __restrict__ off) {
    int e = blockIdx.x * 256 + threadIdx.x;
    if (e < NE) atomicAdd(&off[dst[e]], 1);
}

// ---- 3-phase multi-block exclusive scan of off[0..NN) ----
__global__ __launch_bounds__(256) void scan_p1(const int* __restrict__ off, int* __restrict__ bsum) {
    __shared__ int s[256];
    int b = blockIdx.x, tid = threadIdx.x;
    int i0 = b * SCB + tid * 2;
    int v = 0;
    if (i0 < NN) v += off[i0];
    if (i0 + 1 < NN) v += off[i0 + 1];
    s[tid] = v;
    __syncthreads();
    for (int d = 128; d > 0; d >>= 1) {
        if (tid < d) s[tid] += s[tid + d];
        __syncthreads();
    }
    if (tid == 0) bsum[b] = s[0];
}

__global__ __launch_bounds__(512) void scan_p2(const int* __restrict__ bsum, int* __restrict__ bpre,
                                               int* __restrict__ off) {
    __shared__ int s[512];
    int tid = threadIdx.x;
    int v = (tid < SNB) ? bsum[tid] : 0;
    s[tid] = v;
    __syncthreads();
    for (int d = 1; d < 512; d <<= 1) {
        int u = (tid >= d) ? s[tid - d] : 0;
        __syncthreads();
        s[tid] += u;
        __syncthreads();
    }
    bpre[tid] = s[tid] - v;  // exclusive
    if (tid == 511) off[NN] = s[511];  // total edges
}

__global__ __launch_bounds__(512) void scan_p3(int* __restrict__ off, const int* __restrict__ bpre) {
    __shared__ int s[512];
    int b = blockIdx.x, tid = threadIdx.x;
    int i = b * SCB + tid;
    int v = (i < NN) ? off[i] : 0;
    s[tid] = v;
    __syncthreads();
    for (int d = 1; d < 512; d <<= 1) {
        int u = (tid >= d) ? s[tid - d] : 0;
        __syncthreads();
        s[tid] += u;
        __syncthreads();
    }
    if (i < NN) off[i] = s[tid] - v + bpre[b];
}

__global__ void fill_adj(const int* __restrict__ src, const int* __restrict__ dst,
                         const int* __restrict__ off, int* __restrict__ cursor,
                         int* __restrict__ adjsrc) {
    int e = blockIdx.x * 256 + threadIdx.x;
    if (e < NE) {
        int d = dst[e];
        int p = atomicAdd(&cursor[d], 1);
        adjsrc[off[d] + p] = src[e];
    }
}

// degf[t][i] = 1 + #{in-edges (j->i) : ts[j] <= t}; one histogram pass per node
__global__ __launch_bounds__(256) void degf_hist(const int* __restrict__ off, const int* __restrict__ adjsrc,
                                                 const int* __restrict__ ts, float* __restrict__ degf) {
    __shared__ unsigned short sh[TT * 256];
    int tid = threadIdx.x;
    int i = blockIdx.x * 256 + tid;
    for (int t = 0; t < TT; ++t) sh[t * 256 + tid] = 0;
    if (i >= NN) return;
    int e0 = off[i], e1 = off[i + 1];
    for (int e = e0; e < e1; ++e) {
        int tj = ts[adjsrc[e]];
        sh[tj * 256 + tid]++;
    }
    int cum = 1;
    for (int t = 0; t < TT; ++t) {
        cum += sh[t * 256 + tid];
        degf[(size_t)t * NN + i] = (float)cum;
    }
}

// ---------------- counting sort of nodes by time bucket (no global atomics) ----------------
__global__ __launch_bounds__(256) void hist_rank(const int* __restrict__ ts,
                                                 int* __restrict__ cnt, int* __restrict__ rank) {
    __shared__ int h[TT];
    int tid = threadIdx.x, b = blockIdx.x;
    if (tid < TT) h[tid] = 0;
    __syncthreads();
    int i = b * 256 + tid;
    if (i < NN) {
        int t = ts[i];
        rank[i] = atomicAdd(&h[t], 1);   // LDS atomic: cheap
    }
    __syncthreads();
    if (tid < TT) cnt[b * TT + tid] = h[tid];
}

__global__ __launch_bounds__(256) void bucket_scan(const int* __restrict__ cnt,
                                                   int* __restrict__ basecol, int* __restrict__ bcnt) {
    __shared__ int s[256];
    int t = blockIdx.x, tid = threadIdx.x;
    const int CH = (HB + 255) / 256; // 4
    int b0 = tid * CH;
    int loc[CH];
    int sum = 0;
    for (int u = 0; u < CH; ++u) {
        int b = b0 + u;
        int v = (b < HB) ? cnt[b * TT + t] : 0;
        loc[u] = sum;
        sum += v;
    }
    s[tid] = sum;
    __syncthreads();
    for (int d = 1; d < 256; d <<= 1) {
        int u = (tid >= d) ? s[tid - d] : 0;
        __syncthreads();
        s[tid] += u;
        __syncthreads();
    }
    int base = s[tid] - sum;   // exclusive prefix for this thread's chunk
    for (int u = 0; u < CH; ++u) {
        int b = b0 + u;
        if (b < HB) basecol[b * TT + t] = base + loc[u];
    }
    if (tid == 255) bcnt[t] = s[255];
}

__global__ __launch_bounds__(256) void perm_scatter(const int* __restrict__ ts, const int* __restrict__ rank,
                                                    const int* __restrict__ basecol, const int* __restrict__ pstart,
                                                    int* __restrict__ perm) {
    int b = blockIdx.x;
    int i = b * 256 + threadIdx.x;
    if (i < NN) {
        int t = ts[i];
        perm[pstart[t] + basecol[b * TT + t] + rank[i]] = i;
    }
}

// ---------------- bucket / tile tables (32-row tiles) ----------------
__global__ void make_tiles(const int* __restrict__ bcnt, int* __restrict__ pstart,
                           int* __restrict__ tile_t, int* __restrict__ tile_r0,
                           int* __restrict__ meta) {
    __shared__ int s_nt[64];
    int t = threadIdx.x; // 64 threads
    int nt = (t < TT) ? (bcnt[t] + 31) / 32 : 0;
    s_nt[t] = nt;
    __syncthreads();
    for (int d = 1; d < 64; d <<= 1) {
        int v = (t >= d) ? s_nt[t - d] : 0;
        __syncthreads();
        s_nt[t] += v;
        __syncthreads();
    }
    int ntbase = s_nt[t] - nt;
    int pbase = ntbase * 32;
    if (t < TT) {
        pstart[t] = pbase;
        for (int u = 0; u < nt; ++u) {
            tile_t[ntbase + u] = t;
            tile_r0[ntbase + u] = pbase + u * 32;
        }
    }
    if (t == 63) {
        meta[0] = s_nt[63];
        meta[1] = s_nt[63] * 32;
        pstart[TT] = s_nt[63] * 32;
    }
}

// ---------------- GRU chain: 1 row/block, thread=(matrix m, gate col c), dot2 inner ----------------
__global__ __launch_bounds__(1024) void gru_evolve(
        const float* __restrict__ initial_w,
        const _Float16* __restrict__ wkp,      // [2][KP][512] half2
        const float* __restrict__ bih, const float* __restrict__ bhh,
        float* __restrict__ W_all) {
    __shared__ float s_w[FF];
    __shared__ __align__(8) _Float16 s_wh[2 * KP];   // 168, padded with zeros
    __shared__ float s_pre[2][512];
    int tid = threadIdx.x;
    int row = blockIdx.x;

    if (tid < FF) {
        float v = initial_w[(size_t)row * FF + tid];
        s_w[tid] = v;
        s_wh[tid] = (_Float16)v;
    } else if (tid < 2 * KP) {
        s_wh[tid] = (_Float16)0.0f;
    }

    int m = (tid >= 498) ? 1 : 0;
    int c = tid - m * 498;
    bool act = tid < 996;
    const half2v* __restrict__ pW = (const half2v*)wkp + (size_t)m * KP * 512 + (act ? c : 0);
    const half2v* s_wh2 = (const half2v*)s_wh;

    float bi_r = 0, bi_z = 0, bi_n = 0, bh_r = 0, bh_z = 0, bh_n = 0;
    if (tid < FF) {
        bi_r = bih[tid]; bi_z = bih[FF + tid]; bi_n = bih[2 * FF + tid];
        bh_r = bhh[tid]; bh_z = bhh[FF + tid]; bh_n = bhh[2 * FF + tid];
    }
    __syncthreads();

    for (int t = 0; t < TT; ++t) {
        if (act) {
            float acc = 0.0f;
            #pragma unroll 4
            for (int kp = 0; kp < KP; ++kp) {
                half2v w2 = s_wh2[kp];
                half2v g2 = pW[(size_t)kp << 9];
                acc = fdot2f(g2, w2, acc);
            }
            s_pre[m][c] = acc;
        }
        __syncthreads();
        if (tid < FF) {
            float i_r = s_pre[0][tid]          + bi_r;
            float h_r = s_pre[1][tid]          + bh_r;
            float i_z = s_pre[0][FF + tid]     + bi_z;
            float h_z = s_pre[1][FF + tid]     + bh_z;
            float i_n = s_pre[0][2 * FF + tid] + bi_n;
            float h_n = s_pre[1][2 * FF + tid] + bh_n;
            float rg = 1.0f / (1.0f + expf(-(i_r + h_r)));
            float zg = 1.0f / (1.0f + expf(-(i_z + h_z)));
            float ng = tanhf(i_n + rg * h_n);
            float wnew = (1.0f - zg) * ng + zg * s_w[tid];
            s_w[tid] = wnew;
            s_wh[tid] = (_Float16)wnew;
            W_all[((size_t)t * FF + row) * FF + tid] = wnew;
        }
        __syncthreads();
    }
}

// ---------------- Mh[t][h][k] (fp16, k padded to 192) = W_t @ projw^T transposed ----------------
__global__ __launch_bounds__(1024) void m_build(const float* __restrict__ W_all,
                                                const float* __restrict__ projwT,
                                                _Float16* __restrict__ Mh) {
    __shared__ __align__(16) float sw[8][168];
    int blk = blockIdx.x;
    int t = blk / 24, rb = blk - t * 24;
    int tid = threadIdx.x;
    int r0 = rb * 8;
    for (int idx = tid; idx < 8 * FF; idx += 1024) {
        int rr = idx / FF, k = idx - rr * FF;
        int r = r0 + rr;
        sw[rr][k] = (r < FF) ? W_all[((size_t)t * FF + r) * FF + k] : 0.0f;
    }
    __syncthreads();
    int rr = tid >> 7, h = tid & 127;
    int r = r0 + rr;
    if (r >= KPAD) return;
    float acc = 0.0f;
    if (r < FF) {
        const float* __restrict__ pw = projwT + h;
        #pragma unroll 4
        for (int c4 = 0; c4 < 164; c4 += 4) {
            float4 w = *(const float4*)&sw[rr][c4];
            acc += w.x * pw[(size_t)(c4 + 0) << 7];
            acc += w.y * pw[(size_t)(c4 + 1) << 7];
            acc += w.z * pw[(size_t)(c4 + 2) << 7];
            acc += w.w * pw[(size_t)(c4 + 3) << 7];
        }
        acc += sw[rr][164] * pw[(size_t)164 << 7];
        acc += sw[rr][165] * pw[(size_t)165 << 7];
    }
    Mh[((size_t)t * HH + h) * KPAD + r] = (_Float16)acc;
}

// ---------------- y build (fp16 gather): y_i = x_i/deg_i + sum norm_ij x_j ----------------
__global__ __launch_bounds__(256) void ybuild(const int* __restrict__ perm, const int* __restrict__ ts,
                                              const half2v* __restrict__ x2,
                                              const int* __restrict__ off, const int* __restrict__ adjsrc,
                                              const float* __restrict__ degf, _Float16* __restrict__ Yh) {
    int r = blockIdx.x * 4 + (threadIdx.x >> 6);
    int lane = threadIdx.x & 63;
    int i = perm[r];
    half2v* yr2 = (half2v*)(Yh + (size_t)r * KPAD);
    if (i < 0) {
        half2v z; z[0] = (_Float16)0.0f; z[1] = (_Float16)0.0f;
        yr2[lane] = z;
        if (lane < 32) yr2[64 + lane] = z;
        return;
    }
    int t = ts[i];
    const float* degt = degf + (size_t)t * NN;
    float degi = degt[i];
    float inv_degi = 1.0f / degi;
    float dinv_i = rsqrtf(degi);
    bool lo = lane < 32;

    const half2v* xi = x2 + (size_t)i * 96;
    float a0x, a0y, a1x = 0.0f, a1y = 0.0f;
    {
        half2v h0 = xi[lane];
        a0x = inv_degi * (float)h0[0];
        a0y = inv_degi * (float)h0[1];
        if (lo) {
            half2v h1 = xi[64 + lane];
            a1x = inv_degi * (float)h1[0];
            a1y = inv_degi * (float)h1[1];
        }
    }
    int e0 = off[i], e1 = off[i + 1];
    for (int e = e0; e < e1; ++e) {
        int j = adjsrc[e];
        if (ts[j] <= t) {
            float nrm = rsqrtf(degt[j]) * dinv_i;
            const half2v* xj = x2 + (size_t)j * 96;
            half2v h0 = xj[lane];
            a0x += nrm * (float)h0[0];
            a0y += nrm * (float)h0[1];
            if (lo) {
                half2v h1 = xj[64 + lane];
                a1x += nrm * (float)h1[0];
                a1y += nrm * (float)h1[1];
            }
        }
    }
    half2v o0;
    o0[0] = (_Float16)a0x;
    o0[1] = (_Float16)a0y;
    yr2[lane] = o0;
    if (lo) {
        half2v o1;
        o1[0] = (_Float16)a1x;
        o1[1] = (_Float16)a1y;
        yr2[64 + lane] = o1;
    }
}

// ---------------- MFMA: P = relu(Y@M_t + pb); logits = P@cls^T + cb ----------------
__global__ __launch_bounds__(256) void gemm_mfma(
        const int* __restrict__ meta, const int* __restrict__ tile_t,
        const int* __restrict__ tile_r0, const int* __restrict__ perm,
        const _Float16* __restrict__ Yh, const _Float16* __restrict__ Mh,
        const float* __restrict__ proj_b, const float* __restrict__ cls_w,
        const float* __restrict__ cls_b, float* __restrict__ out) {
    __shared__ __align__(16) char smraw[32 * 130 * 4];   // 16640 B; Y stage needs 12800
    _Float16* sY = (_Float16*)smraw;   // [32][200] fp16
    float* sP = (float*)smraw;         // [32][130] f32
    int bid = blockIdx.x;
    if (bid >= meta[0]) return;
    int t = tile_t[bid], r0 = tile_r0[bid];
    int tid = threadIdx.x;

    // stage Y tile: 32 rows x 192 fp16 (LDS stride 200 -> only 2-way conflicts)
    {
        const uint4* src = (const uint4*)(Yh + (size_t)r0 * KPAD);
        #pragma unroll
        for (int u = 0; u < 3; ++u) {
            int q = tid + u * 256;          // 0..767
            int row = q / 24, kc = q - row * 24;
            *(uint4*)(sY + row * 200 + kc * 8) = src[row * 24 + kc];
        }
    }
    __syncthreads();

    int lane = tid & 63;
    int w = tid >> 6;          // wave 0..3 -> cols w*32..w*32+31
    int lr = lane & 15;
    int kg = lane >> 4;

    f32x4 acc00 = {0,0,0,0}, acc01 = {0,0,0,0}, acc10 = {0,0,0,0}, acc11 = {0,0,0,0};
    const _Float16* B0 = Mh + ((size_t)t * HH + w * 32 + lr) * KPAD + kg * 8;
    const _Float16* B1 = B0 + 16 * KPAD;
    const _Float16* A0 = sY + lr * 200 + kg * 8;
    const _Float16* A1 = A0 + 16 * 200;

    #pragma unroll
    for (int s = 0; s < 6; ++s) {
        f16x8 a0 = *(const f16x8*)(A0 + s * 32);
        f16x8 a1 = *(const f16x8*)(A1 + s * 32);
        f16x8 b0 = *(const f16x8*)(B0 + s * 32);
        f16x8 b1 = *(const f16x8*)(B1 + s * 32);
        acc00 = __builtin_amdgcn_mfma_f32_16x16x32_f16(a0, b0, acc00, 0, 0, 0);
        acc01 = __builtin_amdgcn_mfma_f32_16x16x32_f16(a0, b1, acc01, 0, 0, 0);
        acc10 = __builtin_amdgcn_mfma_f32_16x16x32_f16(a1, b0, acc10, 0, 0, 0);
        acc11 = __builtin_amdgcn_mfma_f32_16x16x32_f16(a1, b1, acc11, 0, 0, 0);
    }

    float pb0 = proj_b[w * 32 + lr];
    float pb1 = proj_b[w * 32 + 16 + lr];
    __syncthreads();   // K-loop LDS reads finished; reuse as sP
    int prow = kg * 4;
    int col0 = w * 32 + lr;
    #pragma unroll
    for (int r = 0; r < 4; ++r) {
        sP[(prow + r) * 130 + col0]           = fmaxf(acc00[r] + pb0, 0.0f);
        sP[(prow + r) * 130 + col0 + 16]      = fmaxf(acc01[r] + pb1, 0.0f);
        sP[(16 + prow + r) * 130 + col0]      = fmaxf(acc10[r] + pb0, 0.0f);
        sP[(16 + prow + r) * 130 + col0 + 16] = fmaxf(acc11[r] + pb1, 0.0f);
    }
    __syncthreads();

    // logits: thread = row(32) x cc(2) x quarter(4); shuffle-reduce the quarters
    int row = tid >> 3, cc = (tid >> 2) & 1, q = tid & 3;
    const float* pr = sP + row * 130 + q * 32;
    const float* cw = cls_w + cc * HH + q * 32;
    float s = 0.0f;
    #pragma unroll 8
    for (int h = 0; h < 32; ++h) s += pr[h] * cw[h];
    s += __shfl_xor(s, 1);
    s += __shfl_xor(s, 2);
    if (q == 0) {
        int node = perm[r0 + row];
        if (node >= 0) out[(size_t)node * CC + cc] = s + cls_b[cc];
    }
}

// ---------------- host ----------------
extern "C" void kernel_launch(void* const* d_in, const int* in_sizes, int n_in,
                              void* d_out, int out_size, void* d_ws, size_t ws_size,
                              hipStream_t stream) {
    const float* x = (const float*)d_in[0];
    const int* ei = (const int*)d_in[1];
    const int* srcp = ei;
    const int* dstp = ei + NE;
    const int* ts = (const int*)d_in[2];
    const float* initial_w = (const float*)d_in[3];
    const float* wih = (const float*)d_in[4];
    const float* whh = (const float*)d_in[5];
    const float* bih = (const float*)d_in[6];
    const float* bhh = (const float*)d_in[7];
    const float* projw = (const float*)d_in[8];
    const float* projb = (const float*)d_in[9];
    const float* clsw = (const float*)d_in[10];
    const float* clsb = (const float*)d_in[11];
    float* out = (float*)d_out;

    char* base = (char*)d_ws;
    size_t o = 0;
    auto alloc = [&](size_t bytes) { size_t r = o; o = (o + bytes + 255) & ~(size_t)255; return r; };

    float*    W_all  = (float*)   (base + alloc((size_t)TT * FF * FF * 4));
    _Float16* Mh     = (_Float16*)(base + alloc((size_t)TT * HH * KPAD * 2));
    _Float16* wkp    = (_Float16*)(base + alloc((size_t)2 * KP * 512 * 2 * 2));
    float*    projwT = (float*)   (base + alloc((size_t)FF * HH * 4));
    int*      off    = (int*)     (base + alloc((size_t)(NN + 1) * 4));
    int*      cursor = (int*)     (base + alloc((size_t)NN * 4));
    int*      adjsrc = (int*)     (base + alloc((size_t)NE * 4));
    float*    degf   = (float*)   (base + alloc((size_t)TT * NN * 4));
    int*      bcnt   = (int*)     (base + alloc((size_t)TT * 4));
    int*      pstart = (int*)     (base + alloc((size_t)(TT + 1) * 4));
    int*      meta   = (int*)     (base + alloc(2 * 4));
    int*      tile_t = (int*)     (base + alloc((size_t)MAXTILES * 4));
    int*      tile_r0= (int*)     (base + alloc((size_t)MAXTILES * 4));
    int*      perm   = (int*)     (base + alloc((size_t)PADN * 4));
    int*      bsum   = (int*)     (base + alloc((size_t)512 * 4));
    int*      bpre   = (int*)     (base + alloc((size_t)520 * 4));
    int*      cnt    = (int*)     (base + alloc((size_t)HB * TT * 4));
    int*      basecol= (int*)     (base + alloc((size_t)HB * TT * 4));
    int*      rank   = (int*)     (base + alloc((size_t)NN * 4));
    half2v*   x2     = (half2v*)  (base + alloc((size_t)NN * 96 * 4));
    _Float16* Yh     = (_Float16*)(base + alloc((size_t)PADN * KPAD * 2));

    hipMemsetAsync(off, 0, (size_t)(NN + 1) * 4, stream);
    hipMemsetAsync(cursor, 0, (size_t)NN * 4, stream);
    hipMemsetAsync(perm, 0xFF, (size_t)PADN * 4, stream);

    prep_pack<<<420, 256, 0, stream>>>(wih, whh, projw, wkp, projwT);
    x_to_h<<<(NN * 96 + 255) / 256, 256, 0, stream>>>(x, x2);
    count_indeg<<<(NE + 255) / 256, 256, 0, stream>>>(dstp, off);
    hist_rank<<<HB, 256, 0, stream>>>(ts, cnt, rank);
    scan_p1<<<SNB, 256, 0, stream>>>(off, bsum);
    scan_p2<<<1, 512, 0, stream>>>(bsum, bpre, off);
    scan_p3<<<SNB, 512, 0, stream>>>(off, bpre);
    fill_adj<<<(NE + 255) / 256, 256, 0, stream>>>(srcp, dstp, off, cursor, adjsrc);
    degf_hist<<<(NN + 255) / 256, 256, 0, stream>>>(off, adjsrc, ts, degf);
    bucket_scan<<<TT, 256, 0, stream>>>(cnt, basecol, bcnt);
    make_tiles<<<1, 64, 0, stream>>>(bcnt, pstart, tile_t, tile_r0, meta);
    perm_scatter<<<HB, 256, 0, stream>>>(ts, rank, basecol, pstart, perm);

    gru_evolve<<<FF, 1024, 0, stream>>>(initial_w, wkp, bih, bhh, W_all);
    m_build<<<TT * 24, 1024, 0, stream>>>(W_all, projwT, Mh);

    ybuild<<<PADN / 4, 256, 0, stream>>>(perm, ts, x2, off, adjsrc, degf, Yh);

    gemm_mfma<<<MAXTILES, 256, 0, stream>>>(meta, tile_t, tile_r0, perm, Yh, Mh,
                                            projb, clsw, clsb, out);
}

// Round 8
// 446.473 us; speedup vs baseline: 1.2557x; 1.2557x over previous
//
#include <hip/hip_runtime.h>
#include <hip/hip_fp16.h>
#include <math.h>

#define NN 200000
#define NE 500000
#define FF 166
#define HH 128
#define CC 2
#define TT 49
#define GG 498            // 3*FF
#define PADN 203136
#define MAXTILES 6400
#define KP 84             // k-pairs (166 -> 84 half2, padded)
#define KPAD 192          // K padded to 6*32 for MFMA
#define SCB 512           // scan elements per block
#define SNB 391           // ceil(NN/512)
#define HB 782            // ceil(NN/256) histogram blocks

typedef _Float16 half2v __attribute__((ext_vector_type(2)));
typedef _Float16 f16x8 __attribute__((ext_vector_type(8)));
typedef float f32x4 __attribute__((ext_vector_type(4)));

static __device__ __forceinline__ float fdot2f(half2v a, half2v b, float c) {
#if __has_builtin(__builtin_amdgcn_fdot2)
    return __builtin_amdgcn_fdot2(a, b, c, false);
#else
    return c + (float)a.x * (float)b.x + (float)a.y * (float)b.y;
#endif
}

// ---------------- prep: pack GRU weights as [m][kp][512] half2 (k-pairs), fp32 projT ----------------
__global__ void prep_pack(const float* __restrict__ wih, const float* __restrict__ whh,
                          const float* __restrict__ projw,
                          _Float16* __restrict__ wkp, float* __restrict__ projwT) {
    int idx = blockIdx.x * 256 + threadIdx.x;
    const int A = 2 * KP * 512; // 86016 half2 slots
    if (idx < A) {
        int m = idx / (KP * 512);
        int r = idx - m * (KP * 512);
        int kp = r >> 9, c = r & 511;
        const float* Wm = m ? whh : wih;
        float x0 = 0.0f, x1 = 0.0f;
        if (c < GG) {
            int k0 = 2 * kp, k1 = 2 * kp + 1;
            if (k0 < FF) x0 = Wm[c * FF + k0];
            if (k1 < FF) x1 = Wm[c * FF + k1];
        }
        wkp[2 * idx]     = (_Float16)x0;
        wkp[2 * idx + 1] = (_Float16)x1;
    } else if (idx < A + FF * HH) {
        int q = idx - A;
        int k = q >> 7, h = q & 127;
        projwT[q] = projw[h * FF + k];
    }
}

// ---------------- x -> fp16, padded [NN][192] (half2 slots [NN][96]) ----------------
__global__ __launch_bounds__(256) void x_to_h(const float* __restrict__ x, half2v* __restrict__ x2) {
    int idx = blockIdx.x * 256 + threadIdx.x;
    if (idx >= NN * 96) return;
    int row = idx / 96, cp = idx - row * 96;
    int c0 = cp * 2;
    float v0 = (c0 < FF) ? x[(size_t)row * FF + c0] : 0.0f;
    float v1 = (c0 + 1 < FF) ? x[(size_t)row * FF + c0 + 1] : 0.0f;
    half2v h;
    h[0] = (_Float16)v0;
    h[1] = (_Float16)v1;
    x2[idx] = h;
}

// ---------------- CSR build ----------------
__global__ void count_indeg(const int* __restrict__ dst, int* __restrict__ off) {
    int e = blockIdx.x * 256 + threadIdx.x;
    if (e < NE) atomicAdd(&off[dst[e]], 1);
}

// ---- 3-phase multi-block exclusive scan of off[0..NN) ----
__global__ __launch_bounds__(256) void scan_p1(const int* __restrict__ off, int* __restrict__ bsum) {
    __shared__ int s[256];
    int b = blockIdx.x, tid = threadIdx.x;
    int i0 = b * SCB + tid * 2;
    int v = 0;
    if (i0 < NN) v += off[i0];
    if (i0 + 1 < NN) v += off[i0 + 1];
    s[tid] = v;
    __syncthreads();
    for (int d = 128; d > 0; d >>= 1) {
        if (tid < d) s[tid] += s[tid + d];
        __syncthreads();
    }
    if (tid == 0) bsum[b] = s[0];
}

__global__ __launch_bounds__(512) void scan_p2(const int* __restrict__ bsum, int* __restrict__ bpre,
                                               int* __restrict__ off) {
    __shared__ int s[512];
    int tid = threadIdx.x;
    int v = (tid < SNB) ? bsum[tid] : 0;
    s[tid] = v;
    __syncthreads();
    for (int d = 1; d < 512; d <<= 1) {
        int u = (tid >= d) ? s[tid - d] : 0;
        __syncthreads();
        s[tid] += u;
        __syncthreads();
    }
    bpre[tid] = s[tid] - v;  // exclusive
    if (tid == 511) off[NN] = s[511];  // total edges
}

__global__ __launch_bounds__(512) void scan_p3(int* __restrict__ off, const int* __restrict__ bpre) {
    __shared__ int s[512];
    int b = blockIdx.x, tid = threadIdx.x;
    int i = b * SCB + tid;
    int v = (i < NN) ? off[i] : 0;
    s[tid] = v;
    __syncthreads();
    for (int d = 1; d < 512; d <<= 1) {
        int u = (tid >= d) ? s[tid - d] : 0;
        __syncthreads();
        s[tid] += u;
        __syncthreads();
    }
    if (i < NN) off[i] = s[tid] - v + bpre[b];
}

__global__ void fill_adj(const int* __restrict__ src, const int* __restrict__ dst,
                         const int* __restrict__ off, int* __restrict__ cursor,
                         int* __restrict__ adjsrc) {
    int e = blockIdx.x * 256 + threadIdx.x;
    if (e < NE) {
        int d = dst[e];
        int p = atomicAdd(&cursor[d], 1);
        adjsrc[off[d] + p] = src[e];
    }
}

// degf[t][i] = 1 + #{in-edges (j->i) : ts[j] <= t}; one histogram pass per node
__global__ __launch_bounds__(256) void degf_hist(const int* __restrict__ off, const int* __restrict__ adjsrc,
                                                 const int* __restrict__ ts, float* __restrict__ degf) {
    __shared__ unsigned short sh[TT * 256];
    int tid = threadIdx.x;
    int i = blockIdx.x * 256 + tid;
    for (int t = 0; t < TT; ++t) sh[t * 256 + tid] = 0;
    if (i >= NN) return;
    int e0 = off[i], e1 = off[i + 1];
    for (int e = e0; e < e1; ++e) {
        int tj = ts[adjsrc[e]];
        sh[tj * 256 + tid]++;
    }
    int cum = 1;
    for (int t = 0; t < TT; ++t) {
        cum += sh[t * 256 + tid];
        degf[(size_t)t * NN + i] = (float)cum;
    }
}

// ---------------- counting sort of nodes by time bucket (no global atomics) ----------------
__global__ __launch_bounds__(256) void hist_rank(const int* __restrict__ ts,
                                                 int* __restrict__ cnt, int* __restrict__ rank) {
    __shared__ int h[TT];
    int tid = threadIdx.x, b = blockIdx.x;
    if (tid < TT) h[tid] = 0;
    __syncthreads();
    int i = b * 256 + tid;
    if (i < NN) {
        int t = ts[i];
        rank[i] = atomicAdd(&h[t], 1);   // LDS atomic: cheap
    }
    __syncthreads();
    if (tid < TT) cnt[b * TT + tid] = h[tid];
}

__global__ __launch_bounds__(256) void bucket_scan(const int* __restrict__ cnt,
                                                   int* __restrict__ basecol, int* __restrict__ bcnt) {
    __shared__ int s[256];
    int t = blockIdx.x, tid = threadIdx.x;
    const int CH = (HB + 255) / 256; // 4
    int b0 = tid * CH;
    int loc[CH];
    int sum = 0;
    for (int u = 0; u < CH; ++u) {
        int b = b0 + u;
        int v = (b < HB) ? cnt[b * TT + t] : 0;
        loc[u] = sum;
        sum += v;
    }
    s[tid] = sum;
    __syncthreads();
    for (int d = 1; d < 256; d <<= 1) {
        int u = (tid >= d) ? s[tid - d] : 0;
        __syncthreads();
        s[tid] += u;
        __syncthreads();
    }
    int base = s[tid] - sum;   // exclusive prefix for this thread's chunk
    for (int u = 0; u < CH; ++u) {
        int b = b0 + u;
        if (b < HB) basecol[b * TT + t] = base + loc[u];
    }
    if (tid == 255) bcnt[t] = s[255];
}

__global__ __launch_bounds__(256) void perm_scatter(const int* __restrict__ ts, const int* __restrict__ rank,
                                                    const int* __restrict__ basecol, const int* __restrict__ pstart,
                                                    int* __restrict__ perm) {
    int b = blockIdx.x;
    int i = b * 256 + threadIdx.x;
    if (i < NN) {
        int t = ts[i];
        perm[pstart[t] + basecol[b * TT + t] + rank[i]] = i;
    }
}

// ---------------- bucket / tile tables (32-row tiles) ----------------
__global__ void make_tiles(const int* __restrict__ bcnt, int* __restrict__ pstart,
                           int* __restrict__ tile_t, int* __restrict__ tile_r0,
                           int* __restrict__ meta) {
    __shared__ int s_nt[64];
    int t = threadIdx.x; // 64 threads
    int nt = (t < TT) ? (bcnt[t] + 31) / 32 : 0;
    s_nt[t] = nt;
    __syncthreads();
    for (int d = 1; d < 64; d <<= 1) {
        int v = (t >= d) ? s_nt[t - d] : 0;
        __syncthreads();
        s_nt[t] += v;
        __syncthreads();
    }
    int ntbase = s_nt[t] - nt;
    int pbase = ntbase * 32;
    if (t < TT) {
        pstart[t] = pbase;
        for (int u = 0; u < nt; ++u) {
            tile_t[ntbase + u] = t;
            tile_r0[ntbase + u] = pbase + u * 32;
        }
    }
    if (t == 63) {
        meta[0] = s_nt[63];
        meta[1] = s_nt[63] * 32;
        pstart[TT] = s_nt[63] * 32;
    }
}

// ---------------- GRU chain: 1 row/block, weights REGISTER-RESIDENT (2 cols/thread) ----------------
__global__ __launch_bounds__(512) void gru_evolve(
        const float* __restrict__ initial_w,
        const _Float16* __restrict__ wkp,      // [2][KP][512] half2
        const float* __restrict__ bih, const float* __restrict__ bhh,
        float* __restrict__ W_all) {
    __shared__ float s_w[FF];
    __shared__ __align__(16) _Float16 s_wh[2 * KP];   // 168 halfs = 21 f16x8 chunks
    __shared__ float s_pre[2][512];
    int tid = threadIdx.x;
    int row = blockIdx.x;

    if (tid < FF) {
        float v = initial_w[(size_t)row * FF + tid];
        s_w[tid] = v;
        s_wh[tid] = (_Float16)v;
    } else if (tid < 2 * KP) {
        s_wh[tid] = (_Float16)0.0f;
    }

    // thread -> two adjacent combined gate-cols cc0 = 2*tid, 2*tid+1 (0..995).
    // 498 is even, so a thread never straddles the wih/whh boundary.
    int cc0 = tid * 2;
    bool act = cc0 < 996;
    int m = (cc0 >= 498) ? 1 : 0;
    int c0 = act ? (cc0 - m * 498) : 0;

    // one-time: stream both weight columns into registers (84 half2 each)
    half2v wr0[KP], wr1[KP];
    {
        const half2v* __restrict__ pW =
            (const half2v*)wkp + (size_t)(act ? m : 0) * (KP * 512) + c0;
        #pragma unroll
        for (int kp = 0; kp < KP; ++kp) {
            wr0[kp] = pW[(size_t)(kp << 9)];
            wr1[kp] = pW[(size_t)(kp << 9) + 1];
        }
    }

    float bi_r = 0, bi_z = 0, bi_n = 0, bh_r = 0, bh_z = 0, bh_n = 0;
    if (tid < FF) {
        bi_r = bih[tid]; bi_z = bih[FF + tid]; bi_n = bih[2 * FF + tid];
        bh_r = bhh[tid]; bh_z = bhh[FF + tid]; bh_n = bhh[2 * FF + tid];
    }
    __syncthreads();

    const f16x8* s_wh8 = (const f16x8*)s_wh;   // 21 chunks
    for (int t = 0; t < TT; ++t) {
        if (act) {
            float a0 = 0.0f, a1 = 0.0f;
            #pragma unroll
            for (int q = 0; q < 21; ++q) {
                f16x8 w8 = s_wh8[q];     // broadcast ds_read_b128
                half2v h0 = __builtin_shufflevector(w8, w8, 0, 1);
                half2v h1 = __builtin_shufflevector(w8, w8, 2, 3);
                half2v h2 = __builtin_shufflevector(w8, w8, 4, 5);
                half2v h3 = __builtin_shufflevector(w8, w8, 6, 7);
                a0 = fdot2f(wr0[4 * q + 0], h0, a0);  a1 = fdot2f(wr1[4 * q + 0], h0, a1);
                a0 = fdot2f(wr0[4 * q + 1], h1, a0);  a1 = fdot2f(wr1[4 * q + 1], h1, a1);
                a0 = fdot2f(wr0[4 * q + 2], h2, a0);  a1 = fdot2f(wr1[4 * q + 2], h2, a1);
                a0 = fdot2f(wr0[4 * q + 3], h3, a0);  a1 = fdot2f(wr1[4 * q + 3], h3, a1);
            }
            s_pre[m][c0]     = a0;
            s_pre[m][c0 + 1] = a1;
        }
        __syncthreads();   // pre-activations ready
        if (tid < FF) {
            float i_r = s_pre[0][tid]          + bi_r;
            float h_r = s_pre[1][tid]          + bh_r;
            float i_z = s_pre[0][FF + tid]     + bi_z;
            float h_z = s_pre[1][FF + tid]     + bh_z;
            float i_n = s_pre[0][2 * FF + tid] + bi_n;
            float h_n = s_pre[1][2 * FF + tid] + bh_n;
            float rg = 1.0f / (1.0f + expf(-(i_r + h_r)));
            float zg = 1.0f / (1.0f + expf(-(i_z + h_z)));
            float ng = tanhf(i_n + rg * h_n);
            float wnew = (1.0f - zg) * ng + zg * s_w[tid];
            s_w[tid] = wnew;
            s_wh[tid] = (_Float16)wnew;
            W_all[((size_t)t * FF + row) * FF + tid] = wnew;
        }
        __syncthreads();   // new W row visible before next matvec
    }
}

// ---------------- Mh[t][h][k] (fp16, k padded to 192) = W_t @ projw^T transposed ----------------
__global__ __launch_bounds__(1024) void m_build(const float* __restrict__ W_all,
                                                const float* __restrict__ projwT,
                                                _Float16* __restrict__ Mh) {
    __shared__ __align__(16) float sw[8][168];
    int blk = blockIdx.x;
    int t = blk / 24, rb = blk - t * 24;
    int tid = threadIdx.x;
    int r0 = rb * 8;
    for (int idx = tid; idx < 8 * FF; idx += 1024) {
        int rr = idx / FF, k = idx - rr * FF;
        int r = r0 + rr;
        sw[rr][k] = (r < FF) ? W_all[((size_t)t * FF + r) * FF + k] : 0.0f;
    }
    __syncthreads();
    int rr = tid >> 7, h = tid & 127;
    int r = r0 + rr;
    if (r >= KPAD) return;
    float acc = 0.0f;
    if (r < FF) {
        const float* __restrict__ pw = projwT + h;
        #pragma unroll 4
        for (int c4 = 0; c4 < 164; c4 += 4) {
            float4 w = *(const float4*)&sw[rr][c4];
            acc += w.x * pw[(size_t)(c4 + 0) << 7];
            acc += w.y * pw[(size_t)(c4 + 1) << 7];
            acc += w.z * pw[(size_t)(c4 + 2) << 7];
            acc += w.w * pw[(size_t)(c4 + 3) << 7];
        }
        acc += sw[rr][164] * pw[(size_t)164 << 7];
        acc += sw[rr][165] * pw[(size_t)165 << 7];
    }
    Mh[((size_t)t * HH + h) * KPAD + r] = (_Float16)acc;
}

// ---------------- y build (fp16 gather): y_i = x_i/deg_i + sum norm_ij x_j ----------------
__global__ __launch_bounds__(256) void ybuild(const int* __restrict__ perm, const int* __restrict__ ts,
                                              const half2v* __restrict__ x2,
                                              const int* __restrict__ off, const int* __restrict__ adjsrc,
                                              const float* __restrict__ degf, _Float16* __restrict__ Yh) {
    int r = blockIdx.x * 4 + (threadIdx.x >> 6);
    int lane = threadIdx.x & 63;
    int i = perm[r];
    half2v* yr2 = (half2v*)(Yh + (size_t)r * KPAD);
    if (i < 0) {
        half2v z; z[0] = (_Float16)0.0f; z[1] = (_Float16)0.0f;
        yr2[lane] = z;
        if (lane < 32) yr2[64 + lane] = z;
        return;
    }
    int t = ts[i];
    const float* degt = degf + (size_t)t * NN;
    float degi = degt[i];
    float inv_degi = 1.0f / degi;
    float dinv_i = rsqrtf(degi);
    bool lo = lane < 32;

    const half2v* xi = x2 + (size_t)i * 96;
    float a0x, a0y, a1x = 0.0f, a1y = 0.0f;
    {
        half2v h0 = xi[lane];
        a0x = inv_degi * (float)h0[0];
        a0y = inv_degi * (float)h0[1];
        if (lo) {
            half2v h1 = xi[64 + lane];
            a1x = inv_degi * (float)h1[0];
            a1y = inv_degi * (float)h1[1];
        }
    }
    int e0 = off[i], e1 = off[i + 1];
    for (int e = e0; e < e1; ++e) {
        int j = adjsrc[e];
        if (ts[j] <= t) {
            float nrm = rsqrtf(degt[j]) * dinv_i;
            const half2v* xj = x2 + (size_t)j * 96;
            half2v h0 = xj[lane];
            a0x += nrm * (float)h0[0];
            a0y += nrm * (float)h0[1];
            if (lo) {
                half2v h1 = xj[64 + lane];
                a1x += nrm * (float)h1[0];
                a1y += nrm * (float)h1[1];
            }
        }
    }
    half2v o0;
    o0[0] = (_Float16)a0x;
    o0[1] = (_Float16)a0y;
    yr2[lane] = o0;
    if (lo) {
        half2v o1;
        o1[0] = (_Float16)a1x;
        o1[1] = (_Float16)a1y;
        yr2[64 + lane] = o1;
    }
}

// ---------------- MFMA: P = relu(Y@M_t + pb); logits = P@cls^T + cb ----------------
__global__ __launch_bounds__(256) void gemm_mfma(
        const int* __restrict__ meta, const int* __restrict__ tile_t,
        const int* __restrict__ tile_r0, const int* __restrict__ perm,
        const _Float16* __restrict__ Yh, const _Float16* __restrict__ Mh,
        const float* __restrict__ proj_b, const float* __restrict__ cls_w,
        const float* __restrict__ cls_b, float* __restrict__ out) {
    __shared__ __align__(16) char smraw[32 * 130 * 4];   // 16640 B; Y stage needs 12800
    _Float16* sY = (_Float16*)smraw;   // [32][200] fp16
    float* sP = (float*)smraw;         // [32][130] f32
    int bid = blockIdx.x;
    if (bid >= meta[0]) return;
    int t = tile_t[bid], r0 = tile_r0[bid];
    int tid = threadIdx.x;

    // stage Y tile: 32 rows x 192 fp16 (LDS stride 200 -> only 2-way conflicts)
    {
        const uint4* src = (const uint4*)(Yh + (size_t)r0 * KPAD);
        #pragma unroll
        for (int u = 0; u < 3; ++u) {
            int q = tid + u * 256;          // 0..767
            int row = q / 24, kc = q - row * 24;
            *(uint4*)(sY + row * 200 + kc * 8) = src[row * 24 + kc];
        }
    }
    __syncthreads();

    int lane = tid & 63;
    int w = tid >> 6;          // wave 0..3 -> cols w*32..w*32+31
    int lr = lane & 15;
    int kg = lane >> 4;

    f32x4 acc00 = {0,0,0,0}, acc01 = {0,0,0,0}, acc10 = {0,0,0,0}, acc11 = {0,0,0,0};
    const _Float16* B0 = Mh + ((size_t)t * HH + w * 32 + lr) * KPAD + kg * 8;
    const _Float16* B1 = B0 + 16 * KPAD;
    const _Float16* A0 = sY + lr * 200 + kg * 8;
    const _Float16* A1 = A0 + 16 * 200;

    #pragma unroll
    for (int s = 0; s < 6; ++s) {
        f16x8 a0 = *(const f16x8*)(A0 + s * 32);
        f16x8 a1 = *(const f16x8*)(A1 + s * 32);
        f16x8 b0 = *(const f16x8*)(B0 + s * 32);
        f16x8 b1 = *(const f16x8*)(B1 + s * 32);
        acc00 = __builtin_amdgcn_mfma_f32_16x16x32_f16(a0, b0, acc00, 0, 0, 0);
        acc01 = __builtin_amdgcn_mfma_f32_16x16x32_f16(a0, b1, acc01, 0, 0, 0);
        acc10 = __builtin_amdgcn_mfma_f32_16x16x32_f16(a1, b0, acc10, 0, 0, 0);
        acc11 = __builtin_amdgcn_mfma_f32_16x16x32_f16(a1, b1, acc11, 0, 0, 0);
    }

    float pb0 = proj_b[w * 32 + lr];
    float pb1 = proj_b[w * 32 + 16 + lr];
    __syncthreads();   // K-loop LDS reads finished; reuse as sP
    int prow = kg * 4;
    int col0 = w * 32 + lr;
    #pragma unroll
    for (int r = 0; r < 4; ++r) {
        sP[(prow + r) * 130 + col0]           = fmaxf(acc00[r] + pb0, 0.0f);
        sP[(prow + r) * 130 + col0 + 16]      = fmaxf(acc01[r] + pb1, 0.0f);
        sP[(16 + prow + r) * 130 + col0]      = fmaxf(acc10[r] + pb0, 0.0f);
        sP[(16 + prow + r) * 130 + col0 + 16] = fmaxf(acc11[r] + pb1, 0.0f);
    }
    __syncthreads();

    // logits: thread = row(32) x cc(2) x quarter(4); shuffle-reduce the quarters
    int row = tid >> 3, cc = (tid >> 2) & 1, q = tid & 3;
    const float* pr = sP + row * 130 + q * 32;
    const float* cw = cls_w + cc * HH + q * 32;
    float s = 0.0f;
    #pragma unroll 8
    for (int h = 0; h < 32; ++h) s += pr[h] * cw[h];
    s += __shfl_xor(s, 1);
    s += __shfl_xor(s, 2);
    if (q == 0) {
        int node = perm[r0 + row];
        if (node >= 0) out[(size_t)node * CC + cc] = s + cls_b[cc];
    }
}

// ---------------- host ----------------
extern "C" void kernel_launch(void* const* d_in, const int* in_sizes, int n_in,
                              void* d_out, int out_size, void* d_ws, size_t ws_size,
                              hipStream_t stream) {
    const float* x = (const float*)d_in[0];
    const int* ei = (const int*)d_in[1];
    const int* srcp = ei;
    const int* dstp = ei + NE;
    const int* ts = (const int*)d_in[2];
    const float* initial_w = (const float*)d_in[3];
    const float* wih = (const float*)d_in[4];
    const float* whh = (const float*)d_in[5];
    const float* bih = (const float*)d_in[6];
    const float* bhh = (const float*)d_in[7];
    const float* projw = (const float*)d_in[8];
    const float* projb = (const float*)d_in[9];
    const float* clsw = (const float*)d_in[10];
    const float* clsb = (const float*)d_in[11];
    float* out = (float*)d_out;

    char* base = (char*)d_ws;
    size_t o = 0;
    auto alloc = [&](size_t bytes) { size_t r = o; o = (o + bytes + 255) & ~(size_t)255; return r; };

    float*    W_all  = (float*)   (base + alloc((size_t)TT * FF * FF * 4));
    _Float16* Mh     = (_Float16*)(base + alloc((size_t)TT * HH * KPAD * 2));
    _Float16* wkp    = (_Float16*)(base + alloc((size_t)2 * KP * 512 * 2 * 2));
    float*    projwT = (float*)   (base + alloc((size_t)FF * HH * 4));
    int*      off    = (int*)     (base + alloc((size_t)(NN + 1) * 4));
    int*      cursor = (int*)     (base + alloc((size_t)NN * 4));
    int*      adjsrc = (int*)     (base + alloc((size_t)NE * 4));
    float*    degf   = (float*)   (base + alloc((size_t)TT * NN * 4));
    int*      bcnt   = (int*)     (base + alloc((size_t)TT * 4));
    int*      pstart = (int*)     (base + alloc((size_t)(TT + 1) * 4));
    int*      meta   = (int*)     (base + alloc(2 * 4));
    int*      tile_t = (int*)     (base + alloc((size_t)MAXTILES * 4));
    int*      tile_r0= (int*)     (base + alloc((size_t)MAXTILES * 4));
    int*      perm   = (int*)     (base + alloc((size_t)PADN * 4));
    int*      bsum   = (int*)     (base + alloc((size_t)512 * 4));
    int*      bpre   = (int*)     (base + alloc((size_t)520 * 4));
    int*      cnt    = (int*)     (base + alloc((size_t)HB * TT * 4));
    int*      basecol= (int*)     (base + alloc((size_t)HB * TT * 4));
    int*      rank   = (int*)     (base + alloc((size_t)NN * 4));
    half2v*   x2     = (half2v*)  (base + alloc((size_t)NN * 96 * 4));
    _Float16* Yh     = (_Float16*)(base + alloc((size_t)PADN * KPAD * 2));

    hipMemsetAsync(off, 0, (size_t)(NN + 1) * 4, stream);
    hipMemsetAsync(cursor, 0, (size_t)NN * 4, stream);
    hipMemsetAsync(perm, 0xFF, (size_t)PADN * 4, stream);

    prep_pack<<<420, 256, 0, stream>>>(wih, whh, projw, wkp, projwT);
    x_to_h<<<(NN * 96 + 255) / 256, 256, 0, stream>>>(x, x2);
    count_indeg<<<(NE + 255) / 256, 256, 0, stream>>>(dstp, off);
    hist_rank<<<HB, 256, 0, stream>>>(ts, cnt, rank);
    scan_p1<<<SNB, 256, 0, stream>>>(off, bsum);
    scan_p2<<<1, 512, 0, stream>>>(bsum, bpre, off);
    scan_p3<<<SNB, 512, 0, stream>>>(off, bpre);
    fill_adj<<<(NE + 255) / 256, 256, 0, stream>>>(srcp, dstp, off, cursor, adjsrc);
    degf_hist<<<(NN + 255) / 256, 256, 0, stream>>>(off, adjsrc, ts, degf);
    bucket_scan<<<TT, 256, 0, stream>>>(cnt, basecol, bcnt);
    make_tiles<<<1, 64, 0, stream>>>(bcnt, pstart, tile_t, tile_r0, meta);
    perm_scatter<<<HB, 256, 0, stream>>>(ts, rank, basecol, pstart, perm);

    gru_evolve<<<FF, 512, 0, stream>>>(initial_w, wkp, bih, bhh, W_all);
    m_build<<<TT * 24, 1024, 0, stream>>>(W_all, projwT, Mh);

    ybuild<<<PADN / 4, 256, 0, stream>>>(perm, ts, x2, off, adjsrc, degf, Yh);

    gemm_mfma<<<MAXTILES, 256, 0, stream>>>(meta, tile_t, tile_r0, perm, Yh, Mh,
                                            projb, clsw, clsb, out);
}

// Round 9
// 392.638 us; speedup vs baseline: 1.4278x; 1.1371x over previous
//
#include <hip/hip_runtime.h>
#include <hip/hip_fp16.h>
#include <math.h>

#define NN 200000
#define NE 500000
#define FF 166
#define HH 128
#define CC 2
#define TT 49
#define GG 498            // 3*FF
#define PADN 203136
#define MAXTILES 6400
#define KP 84             // k-pairs (166 -> 84 half2, padded)
#define KPAD 192          // K padded to 6*32 for MFMA
#define SCB 512           // scan elements per block
#define SNB 391           // ceil(NN/512)
#define HB 782            // ceil(NN/256) histogram blocks

typedef _Float16 half2v __attribute__((ext_vector_type(2)));
typedef _Float16 f16x8 __attribute__((ext_vector_type(8)));
typedef float f32x4 __attribute__((ext_vector_type(4)));

static __device__ __forceinline__ float fdot2f(half2v a, half2v b, float c) {
#if __has_builtin(__builtin_amdgcn_fdot2)
    return __builtin_amdgcn_fdot2(a, b, c, false);
#else
    return c + (float)a.x * (float)b.x + (float)a.y * (float)b.y;
#endif
}

// ---------------- prep: pack GRU weights as [m][kp][512] half2 (k-pairs), fp32 projT ----------------
__global__ void prep_pack(const float* __restrict__ wih, const float* __restrict__ whh,
                          const float* __restrict__ projw,
                          _Float16* __restrict__ wkp, float* __restrict__ projwT) {
    int idx = blockIdx.x * 256 + threadIdx.x;
    const int A = 2 * KP * 512; // 86016 half2 slots
    if (idx < A) {
        int m = idx / (KP * 512);
        int r = idx - m * (KP * 512);
        int kp = r >> 9, c = r & 511;
        const float* Wm = m ? whh : wih;
        float x0 = 0.0f, x1 = 0.0f;
        if (c < GG) {
            int k0 = 2 * kp, k1 = 2 * kp + 1;
            if (k0 < FF) x0 = Wm[c * FF + k0];
            if (k1 < FF) x1 = Wm[c * FF + k1];
        }
        wkp[2 * idx]     = (_Float16)x0;
        wkp[2 * idx + 1] = (_Float16)x1;
    } else if (idx < A + FF * HH) {
        int q = idx - A;
        int k = q >> 7, h = q & 127;
        projwT[q] = projw[h * FF + k];
    }
}

// ---------------- x -> fp16, padded [NN][192] (half2 slots [NN][96]) ----------------
__global__ __launch_bounds__(256) void x_to_h(const float* __restrict__ x, half2v* __restrict__ x2) {
    int idx = blockIdx.x * 256 + threadIdx.x;
    if (idx >= NN * 96) return;
    int row = idx / 96, cp = idx - row * 96;
    int c0 = cp * 2;
    float v0 = (c0 < FF) ? x[(size_t)row * FF + c0] : 0.0f;
    float v1 = (c0 + 1 < FF) ? x[(size_t)row * FF + c0 + 1] : 0.0f;
    half2v h;
    h[0] = (_Float16)v0;
    h[1] = (_Float16)v1;
    x2[idx] = h;
}

// ---------------- CSR build ----------------
__global__ void count_indeg(const int* __restrict__ dst, int* __restrict__ off) {
    int e = blockIdx.x * 256 + threadIdx.x;
    if (e < NE) atomicAdd(&off[dst[e]], 1);
}

// ---- 3-phase multi-block exclusive scan of off[0..NN) ----
__global__ __launch_bounds__(256) void scan_p1(const int* __restrict__ off, int* __restrict__ bsum) {
    __shared__ int s[256];
    int b = blockIdx.x, tid = threadIdx.x;
    int i0 = b * SCB + tid * 2;
    int v = 0;
    if (i0 < NN) v += off[i0];
    if (i0 + 1 < NN) v += off[i0 + 1];
    s[tid] = v;
    __syncthreads();
    for (int d = 128; d > 0; d >>= 1) {
        if (tid < d) s[tid] += s[tid + d];
        __syncthreads();
    }
    if (tid == 0) bsum[b] = s[0];
}

__global__ __launch_bounds__(512) void scan_p2(const int* __restrict__ bsum, int* __restrict__ bpre,
                                               int* __restrict__ off) {
    __shared__ int s[512];
    int tid = threadIdx.x;
    int v = (tid < SNB) ? bsum[tid] : 0;
    s[tid] = v;
    __syncthreads();
    for (int d = 1; d < 512; d <<= 1) {
        int u = (tid >= d) ? s[tid - d] : 0;
        __syncthreads();
        s[tid] += u;
        __syncthreads();
    }
    bpre[tid] = s[tid] - v;  // exclusive
    if (tid == 511) off[NN] = s[511];  // total edges
}

__global__ __launch_bounds__(512) void scan_p3(int* __restrict__ off, const int* __restrict__ bpre) {
    __shared__ int s[512];
    int b = blockIdx.x, tid = threadIdx.x;
    int i = b * SCB + tid;
    int v = (i < NN) ? off[i] : 0;
    s[tid] = v;
    __syncthreads();
    for (int d = 1; d < 512; d <<= 1) {
        int u = (tid >= d) ? s[tid - d] : 0;
        __syncthreads();
        s[tid] += u;
        __syncthreads();
    }
    if (i < NN) off[i] = s[tid] - v + bpre[b];
}

__global__ void fill_adj(const int* __restrict__ src, const int* __restrict__ dst,
                         const int* __restrict__ off, int* __restrict__ cursor,
                         int* __restrict__ adjsrc, int* __restrict__ dstid) {
    int e = blockIdx.x * 256 + threadIdx.x;
    if (e < NE) {
        int d = dst[e];
        int p = atomicAdd(&cursor[d], 1);
        adjsrc[off[d] + p] = src[e];
        dstid[off[d] + p] = d;
    }
}

// dinvh[t][i] = rsqrt(1 + #{in-edges (j->i): ts[j]<=t}) fp16; selfdeg[i] = exact 1/deg at t=ts[i]
__global__ __launch_bounds__(256) void degf_hist(const int* __restrict__ off, const int* __restrict__ adjsrc,
                                                 const int* __restrict__ ts, _Float16* __restrict__ dinvh,
                                                 float* __restrict__ selfdeg) {
    __shared__ unsigned short sh[TT * 256];
    int tid = threadIdx.x;
    int i = blockIdx.x * 256 + tid;
    for (int t = 0; t < TT; ++t) sh[t * 256 + tid] = 0;
    if (i >= NN) return;
    int tsi = ts[i];
    int e0 = off[i], e1 = off[i + 1];
    for (int e = e0; e < e1; ++e) {
        int tj = ts[adjsrc[e]];
        sh[tj * 256 + tid]++;
    }
    int cum = 1;
    for (int t = 0; t < TT; ++t) {
        cum += sh[t * 256 + tid];
        dinvh[(size_t)t * NN + i] = (_Float16)rsqrtf((float)cum);
        if (t == tsi) selfdeg[i] = 1.0f / (float)cum;
    }
}

// ---------------- per-edge weight precompute: ewp[e] = {src j, fp32 weight} ----------------
__global__ __launch_bounds__(256) void edge_prep(const int* __restrict__ adjsrc, const int* __restrict__ dstid,
                                                 const int* __restrict__ ts, const _Float16* __restrict__ dinvh,
                                                 int2* __restrict__ ewp) {
    int e = blockIdx.x * 256 + threadIdx.x;
    if (e >= NE) return;
    int j = adjsrc[e], i = dstid[e];
    int t = ts[i];
    float w = 0.0f;
    if (ts[j] <= t)
        w = (float)dinvh[(size_t)t * NN + j] * (float)dinvh[(size_t)t * NN + i];
    int2 p;
    p.x = j;
    p.y = __float_as_int(w);
    ewp[e] = p;
}

// ---------------- counting sort of nodes by time bucket (no global atomics) ----------------
__global__ __launch_bounds__(256) void hist_rank(const int* __restrict__ ts,
                                                 int* __restrict__ cnt, int* __restrict__ rank) {
    __shared__ int h[TT];
    int tid = threadIdx.x, b = blockIdx.x;
    if (tid < TT) h[tid] = 0;
    __syncthreads();
    int i = b * 256 + tid;
    if (i < NN) {
        int t = ts[i];
        rank[i] = atomicAdd(&h[t], 1);   // LDS atomic: cheap
    }
    __syncthreads();
    if (tid < TT) cnt[b * TT + tid] = h[tid];
}

__global__ __launch_bounds__(256) void bucket_scan(const int* __restrict__ cnt,
                                                   int* __restrict__ basecol, int* __restrict__ bcnt) {
    __shared__ int s[256];
    int t = blockIdx.x, tid = threadIdx.x;
    const int CH = (HB + 255) / 256; // 4
    int b0 = tid * CH;
    int loc[CH];
    int sum = 0;
    for (int u = 0; u < CH; ++u) {
        int b = b0 + u;
        int v = (b < HB) ? cnt[b * TT + t] : 0;
        loc[u] = sum;
        sum += v;
    }
    s[tid] = sum;
    __syncthreads();
    for (int d = 1; d < 256; d <<= 1) {
        int u = (tid >= d) ? s[tid - d] : 0;
        __syncthreads();
        s[tid] += u;
        __syncthreads();
    }
    int base = s[tid] - sum;   // exclusive prefix for this thread's chunk
    for (int u = 0; u < CH; ++u) {
        int b = b0 + u;
        if (b < HB) basecol[b * TT + t] = base + loc[u];
    }
    if (tid == 255) bcnt[t] = s[255];
}

__global__ __launch_bounds__(256) void perm_scatter(const int* __restrict__ ts, const int* __restrict__ rank,
                                                    const int* __restrict__ basecol, const int* __restrict__ pstart,
                                                    int* __restrict__ perm) {
    int b = blockIdx.x;
    int i = b * 256 + threadIdx.x;
    if (i < NN) {
        int t = ts[i];
        perm[pstart[t] + basecol[b * TT + t] + rank[i]] = i;
    }
}

// ---------------- bucket / tile tables (32-row tiles) ----------------
__global__ void make_tiles(const int* __restrict__ bcnt, int* __restrict__ pstart,
                           int* __restrict__ tile_t, int* __restrict__ tile_r0,
                           int* __restrict__ meta) {
    __shared__ int s_nt[64];
    int t = threadIdx.x; // 64 threads
    int nt = (t < TT) ? (bcnt[t] + 31) / 32 : 0;
    s_nt[t] = nt;
    __syncthreads();
    for (int d = 1; d < 64; d <<= 1) {
        int v = (t >= d) ? s_nt[t - d] : 0;
        __syncthreads();
        s_nt[t] += v;
        __syncthreads();
    }
    int ntbase = s_nt[t] - nt;
    int pbase = ntbase * 32;
    if (t < TT) {
        pstart[t] = pbase;
        for (int u = 0; u < nt; ++u) {
            tile_t[ntbase + u] = t;
            tile_r0[ntbase + u] = pbase + u * 32;
        }
    }
    if (t == 63) {
        meta[0] = s_nt[63];
        meta[1] = s_nt[63] * 32;
        pstart[TT] = s_nt[63] * 32;
    }
}

// ---------------- GRU chain: 1 row/block, weights REGISTER-RESIDENT (2 cols/thread) ----------------
__global__ __launch_bounds__(512) void gru_evolve(
        const float* __restrict__ initial_w,
        const _Float16* __restrict__ wkp,      // [2][KP][512] half2
        const float* __restrict__ bih, const float* __restrict__ bhh,
        float* __restrict__ W_all) {
    __shared__ float s_w[FF];
    __shared__ __align__(16) _Float16 s_wh[2 * KP];   // 168 halfs = 21 f16x8 chunks
    __shared__ float s_pre[2][512];
    int tid = threadIdx.x;
    int row = blockIdx.x;

    if (tid < FF) {
        float v = initial_w[(size_t)row * FF + tid];
        s_w[tid] = v;
        s_wh[tid] = (_Float16)v;
    } else if (tid < 2 * KP) {
        s_wh[tid] = (_Float16)0.0f;
    }

    int cc0 = tid * 2;
    bool act = cc0 < 996;
    int m = (cc0 >= 498) ? 1 : 0;
    int c0 = act ? (cc0 - m * 498) : 0;

    half2v wr0[KP], wr1[KP];
    {
        const half2v* __restrict__ pW =
            (const half2v*)wkp + (size_t)(act ? m : 0) * (KP * 512) + c0;
        #pragma unroll
        for (int kp = 0; kp < KP; ++kp) {
            wr0[kp] = pW[(size_t)(kp << 9)];
            wr1[kp] = pW[(size_t)(kp << 9) + 1];
        }
    }

    float bi_r = 0, bi_z = 0, bi_n = 0, bh_r = 0, bh_z = 0, bh_n = 0;
    if (tid < FF) {
        bi_r = bih[tid]; bi_z = bih[FF + tid]; bi_n = bih[2 * FF + tid];
        bh_r = bhh[tid]; bh_z = bhh[FF + tid]; bh_n = bhh[2 * FF + tid];
    }
    __syncthreads();

    const f16x8* s_wh8 = (const f16x8*)s_wh;   // 21 chunks
    for (int t = 0; t < TT; ++t) {
        if (act) {
            float a0 = 0.0f, a1 = 0.0f;
            #pragma unroll
            for (int q = 0; q < 21; ++q) {
                f16x8 w8 = s_wh8[q];     // broadcast ds_read_b128
                half2v h0 = __builtin_shufflevector(w8, w8, 0, 1);
                half2v h1 = __builtin_shufflevector(w8, w8, 2, 3);
                half2v h2 = __builtin_shufflevector(w8, w8, 4, 5);
                half2v h3 = __builtin_shufflevector(w8, w8, 6, 7);
                a0 = fdot2f(wr0[4 * q + 0], h0, a0);  a1 = fdot2f(wr1[4 * q + 0], h0, a1);
                a0 = fdot2f(wr0[4 * q + 1], h1, a0);  a1 = fdot2f(wr1[4 * q + 1], h1, a1);
                a0 = fdot2f(wr0[4 * q + 2], h2, a0);  a1 = fdot2f(wr1[4 * q + 2], h2, a1);
                a0 = fdot2f(wr0[4 * q + 3], h3, a0);  a1 = fdot2f(wr1[4 * q + 3], h3, a1);
            }
            s_pre[m][c0]     = a0;
            s_pre[m][c0 + 1] = a1;
        }
        __syncthreads();
        if (tid < FF) {
            float i_r = s_pre[0][tid]          + bi_r;
            float h_r = s_pre[1][tid]          + bh_r;
            float i_z = s_pre[0][FF + tid]     + bi_z;
            float h_z = s_pre[1][FF + tid]     + bh_z;
            float i_n = s_pre[0][2 * FF + tid] + bi_n;
            float h_n = s_pre[1][2 * FF + tid] + bh_n;
            float rg = 1.0f / (1.0f + expf(-(i_r + h_r)));
            float zg = 1.0f / (1.0f + expf(-(i_z + h_z)));
            float ng = tanhf(i_n + rg * h_n);
            float wnew = (1.0f - zg) * ng + zg * s_w[tid];
            s_w[tid] = wnew;
            s_wh[tid] = (_Float16)wnew;
            W_all[((size_t)t * FF + row) * FF + tid] = wnew;
        }
        __syncthreads();
    }
}

// ---------------- Mh[t][h][k] (fp16, k padded to 192) = W_t @ projw^T transposed ----------------
__global__ __launch_bounds__(1024) void m_build(const float* __restrict__ W_all,
                                                const float* __restrict__ projwT,
                                                _Float16* __restrict__ Mh) {
    __shared__ __align__(16) float sw[8][168];
    int blk = blockIdx.x;
    int t = blk / 24, rb = blk - t * 24;
    int tid = threadIdx.x;
    int r0 = rb * 8;
    for (int idx = tid; idx < 8 * FF; idx += 1024) {
        int rr = idx / FF, k = idx - rr * FF;
        int r = r0 + rr;
        sw[rr][k] = (r < FF) ? W_all[((size_t)t * FF + r) * FF + k] : 0.0f;
    }
    __syncthreads();
    int rr = tid >> 7, h = tid & 127;
    int r = r0 + rr;
    if (r >= KPAD) return;
    float acc = 0.0f;
    if (r < FF) {
        const float* __restrict__ pw = projwT + h;
        #pragma unroll 4
        for (int c4 = 0; c4 < 164; c4 += 4) {
            float4 w = *(const float4*)&sw[rr][c4];
            acc += w.x * pw[(size_t)(c4 + 0) << 7];
            acc += w.y * pw[(size_t)(c4 + 1) << 7];
            acc += w.z * pw[(size_t)(c4 + 2) << 7];
            acc += w.w * pw[(size_t)(c4 + 3) << 7];
        }
        acc += sw[rr][164] * pw[(size_t)164 << 7];
        acc += sw[rr][165] * pw[(size_t)165 << 7];
    }
    Mh[((size_t)t * HH + h) * KPAD + r] = (_Float16)acc;
}

// ---------------- fused: gather-aggregate into LDS, then MFMA + proj + cls ----------------
__global__ __launch_bounds__(512) void gemm_fused3(
        const int* __restrict__ meta, const int* __restrict__ tile_t,
        const int* __restrict__ tile_r0, const int* __restrict__ perm,
        const float* __restrict__ selfdeg, const half2v* __restrict__ x2,
        const int* __restrict__ off, const int2* __restrict__ ewp,
        const _Float16* __restrict__ Mh, const float* __restrict__ proj_b,
        const float* __restrict__ cls_w, const float* __restrict__ cls_b,
        float* __restrict__ out) {
    __shared__ __align__(16) char smraw[32 * 130 * 4];   // 16640 B (sY needs 12800)
    _Float16* sY = (_Float16*)smraw;   // [32][200] fp16
    float* sP = (float*)smraw;         // [32][130] f32
    int bid = blockIdx.x;
    if (bid >= meta[0]) return;
    int t = tile_t[bid], r0 = tile_r0[bid];
    int tid = threadIdx.x;
    int lane = tid & 63;
    int w = tid >> 6;          // 8 waves
    bool lo = lane < 32;

    // ---- phase 0: aggregation. wave w owns rows w*4 .. w*4+3
    for (int q = 0; q < 4; ++q) {
        int rrow = w * 4 + q;
        int i = perm[r0 + rrow];
        float a0x = 0.f, a0y = 0.f, a1x = 0.f, a1y = 0.f;
        if (i >= 0) {
            float sw = selfdeg[i];
            const half2v* xi = x2 + (size_t)i * 96;
            half2v h0 = xi[lane];
            a0x = sw * (float)h0[0];
            a0y = sw * (float)h0[1];
            if (lo) {
                half2v h1 = xi[64 + lane];
                a1x = sw * (float)h1[0];
                a1y = sw * (float)h1[1];
            }
            int e0 = off[i], e1 = off[i + 1];
            for (int e = e0; e < e1; ++e) {
                int2 p = ewp[e];
                float wv = __int_as_float(p.y);
                if (wv != 0.0f) {
                    const half2v* xj = x2 + (size_t)p.x * 96;
                    half2v g0 = xj[lane];
                    a0x += wv * (float)g0[0];
                    a0y += wv * (float)g0[1];
                    if (lo) {
                        half2v g1 = xj[64 + lane];
                        a1x += wv * (float)g1[0];
                        a1y += wv * (float)g1[1];
                    }
                }
            }
        }
        half2v o0;
        o0[0] = (_Float16)a0x;
        o0[1] = (_Float16)a0y;
        *(half2v*)(sY + rrow * 200 + lane * 2) = o0;
        if (lo) {
            half2v o1;
            o1[0] = (_Float16)a1x;
            o1[1] = (_Float16)a1y;
            *(half2v*)(sY + rrow * 200 + 128 + lane * 2) = o1;
        }
    }
    __syncthreads();

    // ---- phase 1: MFMA. wave w -> 16-col block c0 = w*16
    int lr = lane & 15;
    int kg = lane >> 4;
    int c0 = w * 16;
    f32x4 acc0 = {0, 0, 0, 0}, acc1 = {0, 0, 0, 0};
    const _Float16* B0 = Mh + ((size_t)t * HH + c0 + lr) * KPAD + kg * 8;
    const _Float16* A0 = sY + lr * 200 + kg * 8;
    const _Float16* A1 = A0 + 16 * 200;

    #pragma unroll
    for (int s = 0; s < 6; ++s) {
        f16x8 b0 = *(const f16x8*)(B0 + s * 32);
        f16x8 a0 = *(const f16x8*)(A0 + s * 32);
        f16x8 a1 = *(const f16x8*)(A1 + s * 32);
        acc0 = __builtin_amdgcn_mfma_f32_16x16x32_f16(a0, b0, acc0, 0, 0, 0);
        acc1 = __builtin_amdgcn_mfma_f32_16x16x32_f16(a1, b0, acc1, 0, 0, 0);
    }

    float pb = proj_b[c0 + lr];
    __syncthreads();   // LDS reads done; reuse as sP
    int prow = kg * 4;
    int colw = c0 + lr;
    #pragma unroll
    for (int r = 0; r < 4; ++r) {
        sP[(prow + r) * 130 + colw]      = fmaxf(acc0[r] + pb, 0.0f);
        sP[(16 + prow + r) * 130 + colw] = fmaxf(acc1[r] + pb, 0.0f);
    }
    __syncthreads();

    // ---- phase 2: logits. tid -> row(32) x cc(2) x chunk(8)
    int row = tid >> 4, cc = (tid >> 3) & 1, qq = tid & 7;
    const float* pr = sP + row * 130 + qq * 16;
    const float* cw = cls_w + cc * HH + qq * 16;
    float s = 0.0f;
    #pragma unroll
    for (int h = 0; h < 16; ++h) s += pr[h] * cw[h];
    s += __shfl_xor(s, 1);
    s += __shfl_xor(s, 2);
    s += __shfl_xor(s, 4);
    if (qq == 0) {
        int node = perm[r0 + row];
        if (node >= 0) out[(size_t)node * CC + cc] = s + cls_b[cc];
    }
}

// ---------------- host ----------------
extern "C" void kernel_launch(void* const* d_in, const int* in_sizes, int n_in,
                              void* d_out, int out_size, void* d_ws, size_t ws_size,
                              hipStream_t stream) {
    const float* x = (const float*)d_in[0];
    const int* ei = (const int*)d_in[1];
    const int* srcp = ei;
    const int* dstp = ei + NE;
    const int* ts = (const int*)d_in[2];
    const float* initial_w = (const float*)d_in[3];
    const float* wih = (const float*)d_in[4];
    const float* whh = (const float*)d_in[5];
    const float* bih = (const float*)d_in[6];
    const float* bhh = (const float*)d_in[7];
    const float* projw = (const float*)d_in[8];
    const float* projb = (const float*)d_in[9];
    const float* clsw = (const float*)d_in[10];
    const float* clsb = (const float*)d_in[11];
    float* out = (float*)d_out;

    char* base = (char*)d_ws;
    size_t o = 0;
    auto alloc = [&](size_t bytes) { size_t r = o; o = (o + bytes + 255) & ~(size_t)255; return r; };

    float*    W_all   = (float*)   (base + alloc((size_t)TT * FF * FF * 4));
    _Float16* Mh      = (_Float16*)(base + alloc((size_t)TT * HH * KPAD * 2));
    _Float16* wkp     = (_Float16*)(base + alloc((size_t)2 * KP * 512 * 2 * 2));
    float*    projwT  = (float*)   (base + alloc((size_t)FF * HH * 4));
    int*      off     = (int*)     (base + alloc((size_t)(NN + 1) * 4));
    int*      cursor  = (int*)     (base + alloc((size_t)NN * 4));
    int*      adjsrc  = (int*)     (base + alloc((size_t)NE * 4));
    int*      dstid   = (int*)     (base + alloc((size_t)NE * 4));
    int2*     ewp     = (int2*)    (base + alloc((size_t)NE * 8));
    _Float16* dinvh   = (_Float16*)(base + alloc((size_t)TT * NN * 2));
    float*    selfdeg = (float*)   (base + alloc((size_t)NN * 4));
    int*      bcnt    = (int*)     (base + alloc((size_t)TT * 4));
    int*      pstart  = (int*)     (base + alloc((size_t)(TT + 1) * 4));
    int*      meta    = (int*)     (base + alloc(2 * 4));
    int*      tile_t  = (int*)     (base + alloc((size_t)MAXTILES * 4));
    int*      tile_r0 = (int*)     (base + alloc((size_t)MAXTILES * 4));
    int*      perm    = (int*)     (base + alloc((size_t)PADN * 4));
    int*      bsum    = (int*)     (base + alloc((size_t)512 * 4));
    int*      bpre    = (int*)     (base + alloc((size_t)520 * 4));
    int*      cnt     = (int*)     (base + alloc((size_t)HB * TT * 4));
    int*      basecol = (int*)     (base + alloc((size_t)HB * TT * 4));
    int*      rank    = (int*)     (base + alloc((size_t)NN * 4));
    half2v*   x2      = (half2v*)  (base + alloc((size_t)NN * 96 * 4));

    hipMemsetAsync(off, 0, (size_t)(NN + 1) * 4, stream);
    hipMemsetAsync(cursor, 0, (size_t)NN * 4, stream);
    hipMemsetAsync(perm, 0xFF, (size_t)PADN * 4, stream);

    prep_pack<<<420, 256, 0, stream>>>(wih, whh, projw, wkp, projwT);
    x_to_h<<<(NN * 96 + 255) / 256, 256, 0, stream>>>(x, x2);
    count_indeg<<<(NE + 255) / 256, 256, 0, stream>>>(dstp, off);
    hist_rank<<<HB, 256, 0, stream>>>(ts, cnt, rank);
    scan_p1<<<SNB, 256, 0, stream>>>(off, bsum);
    scan_p2<<<1, 512, 0, stream>>>(bsum, bpre, off);
    scan_p3<<<SNB, 512, 0, stream>>>(off, bpre);
    fill_adj<<<(NE + 255) / 256, 256, 0, stream>>>(srcp, dstp, off, cursor, adjsrc, dstid);
    degf_hist<<<(NN + 255) / 256, 256, 0, stream>>>(off, adjsrc, ts, dinvh, selfdeg);
    edge_prep<<<(NE + 255) / 256, 256, 0, stream>>>(adjsrc, dstid, ts, dinvh, ewp);
    bucket_scan<<<TT, 256, 0, stream>>>(cnt, basecol, bcnt);
    make_tiles<<<1, 64, 0, stream>>>(bcnt, pstart, tile_t, tile_r0, meta);
    perm_scatter<<<HB, 256, 0, stream>>>(ts, rank, basecol, pstart, perm);

    gru_evolve<<<FF, 512, 0, stream>>>(initial_w, wkp, bih, bhh, W_all);
    m_build<<<TT * 24, 1024, 0, stream>>>(W_all, projwT, Mh);

    gemm_fused3<<<MAXTILES, 512, 0, stream>>>(meta, tile_t, tile_r0, perm, selfdeg,
                                              x2, off, ewp, Mh, projb, clsw, clsb, out);
}

// Round 10
// 391.058 us; speedup vs baseline: 1.4336x; 1.0040x over previous
//
#include <hip/hip_runtime.h>
#include <hip/hip_fp16.h>
#include <math.h>

#define NN 200000
#define NE 500000
#define FF 166
#define HH 128
#define CC 2
#define TT 49
#define GG 498            // 3*FF
#define PADN 203136
#define MAXTILES 6400
#define KP 84             // k-pairs (166 -> 84 half2, padded)
#define KPAD 192          // K padded to 6*32 for MFMA
#define SCB 512           // scan elements per block
#define SNB 391           // ceil(NN/512)
#define HB 782            // ceil(NN/256) histogram blocks

typedef _Float16 half2v __attribute__((ext_vector_type(2)));
typedef _Float16 f16x8 __attribute__((ext_vector_type(8)));
typedef float f32x4 __attribute__((ext_vector_type(4)));

static __device__ __forceinline__ float fdot2f(half2v a, half2v b, float c) {
#if __has_builtin(__builtin_amdgcn_fdot2)
    return __builtin_amdgcn_fdot2(a, b, c, false);
#else
    return c + (float)a.x * (float)b.x + (float)a.y * (float)b.y;
#endif
}

// ---------------- prep: pack GRU weights as [m][kp][512] half2 (k-pairs), fp32 projT ----------------
__global__ void prep_pack(const float* __restrict__ wih, const float* __restrict__ whh,
                          const float* __restrict__ projw,
                          _Float16* __restrict__ wkp, float* __restrict__ projwT) {
    int idx = blockIdx.x * 256 + threadIdx.x;
    const int A = 2 * KP * 512; // 86016 half2 slots
    if (idx < A) {
        int m = idx / (KP * 512);
        int r = idx - m * (KP * 512);
        int kp = r >> 9, c = r & 511;
        const float* Wm = m ? whh : wih;
        float x0 = 0.0f, x1 = 0.0f;
        if (c < GG) {
            int k0 = 2 * kp, k1 = 2 * kp + 1;
            if (k0 < FF) x0 = Wm[c * FF + k0];
            if (k1 < FF) x1 = Wm[c * FF + k1];
        }
        wkp[2 * idx]     = (_Float16)x0;
        wkp[2 * idx + 1] = (_Float16)x1;
    } else if (idx < A + FF * HH) {
        int q = idx - A;
        int k = q >> 7, h = q & 127;
        projwT[q] = projw[h * FF + k];
    }
}

// ---------------- x -> fp16, padded [NN][192] (half2 slots [NN][96]) ----------------
__global__ __launch_bounds__(256) void x_to_h(const float* __restrict__ x, half2v* __restrict__ x2) {
    int idx = blockIdx.x * 256 + threadIdx.x;
    if (idx >= NN * 96) return;
    int row = idx / 96, cp = idx - row * 96;
    int c0 = cp * 2;
    float v0 = (c0 < FF) ? x[(size_t)row * FF + c0] : 0.0f;
    float v1 = (c0 + 1 < FF) ? x[(size_t)row * FF + c0 + 1] : 0.0f;
    half2v h;
    h[0] = (_Float16)v0;
    h[1] = (_Float16)v1;
    x2[idx] = h;
}

// ---------------- CSR build ----------------
__global__ void count_indeg(const int* __restrict__ dst, int* __restrict__ off) {
    int e = blockIdx.x * 256 + threadIdx.x;
    if (e < NE) atomicAdd(&off[dst[e]], 1);
}

// ---- 3-phase multi-block exclusive scan of off[0..NN) ----
__global__ __launch_bounds__(256) void scan_p1(const int* __restrict__ off, int* __restrict__ bsum) {
    __shared__ int s[256];
    int b = blockIdx.x, tid = threadIdx.x;
    int i0 = b * SCB + tid * 2;
    int v = 0;
    if (i0 < NN) v += off[i0];
    if (i0 + 1 < NN) v += off[i0 + 1];
    s[tid] = v;
    __syncthreads();
    for (int d = 128; d > 0; d >>= 1) {
        if (tid < d) s[tid] += s[tid + d];
        __syncthreads();
    }
    if (tid == 0) bsum[b] = s[0];
}

__global__ __launch_bounds__(512) void scan_p2(const int* __restrict__ bsum, int* __restrict__ bpre,
                                               int* __restrict__ off) {
    __shared__ int s[512];
    int tid = threadIdx.x;
    int v = (tid < SNB) ? bsum[tid] : 0;
    s[tid] = v;
    __syncthreads();
    for (int d = 1; d < 512; d <<= 1) {
        int u = (tid >= d) ? s[tid - d] : 0;
        __syncthreads();
        s[tid] += u;
        __syncthreads();
    }
    bpre[tid] = s[tid] - v;  // exclusive
    if (tid == 511) off[NN] = s[511];  // total edges
}

__global__ __launch_bounds__(512) void scan_p3(int* __restrict__ off, const int* __restrict__ bpre) {
    __shared__ int s[512];
    int b = blockIdx.x, tid = threadIdx.x;
    int i = b * SCB + tid;
    int v = (i < NN) ? off[i] : 0;
    s[tid] = v;
    __syncthreads();
    for (int d = 1; d < 512; d <<= 1) {
        int u = (tid >= d) ? s[tid - d] : 0;
        __syncthreads();
        s[tid] += u;
        __syncthreads();
    }
    if (i < NN) off[i] = s[tid] - v + bpre[b];
}

__global__ void fill_adj(const int* __restrict__ src, const int* __restrict__ dst,
                         const int* __restrict__ ts,
                         const int* __restrict__ off, int* __restrict__ cursor,
                         int* __restrict__ adjsrc, int* __restrict__ dstid,
                         int* __restrict__ tsrc) {
    int e = blockIdx.x * 256 + threadIdx.x;
    if (e < NE) {
        int d = dst[e];
        int s = src[e];
        int p = atomicAdd(&cursor[d], 1);
        int pos = off[d] + p;
        adjsrc[pos] = s;
        dstid[pos] = d;
        tsrc[pos] = ts[s];
    }
}

// dinvh[t][i] = rsqrt(1 + #{in-edges (j->i): ts[j]<=t}) fp16; selfdeg[i] = exact 1/deg at t=ts[i]
// edge timestamps read STREAMING from tsrc (no dependent random gather).
__global__ __launch_bounds__(256) void degf_hist(const int* __restrict__ off, const int* __restrict__ tsrc,
                                                 const int* __restrict__ ts, _Float16* __restrict__ dinvh,
                                                 float* __restrict__ selfdeg) {
    __shared__ unsigned short sh[TT * 256];
    int tid = threadIdx.x;
    int i = blockIdx.x * 256 + tid;
    for (int t = 0; t < TT; ++t) sh[t * 256 + tid] = 0;
    if (i >= NN) return;
    int tsi = ts[i];
    int e0 = off[i], e1 = off[i + 1];
    for (int e = e0; e < e1; ++e) {
        int tj = tsrc[e];
        sh[tj * 256 + tid]++;
    }
    int cum = 1;
    for (int t = 0; t < TT; ++t) {
        cum += sh[t * 256 + tid];
        dinvh[(size_t)t * NN + i] = (_Float16)rsqrtf((float)cum);
        if (t == tsi) selfdeg[i] = 1.0f / (float)cum;
    }
}

// ---------------- per-edge weight precompute: ewp[e] = {src j, fp32 weight} ----------------
__global__ __launch_bounds__(256) void edge_prep(const int* __restrict__ adjsrc, const int* __restrict__ dstid,
                                                 const int* __restrict__ tsrc,
                                                 const int* __restrict__ ts, const _Float16* __restrict__ dinvh,
                                                 int2* __restrict__ ewp) {
    int e = blockIdx.x * 256 + threadIdx.x;
    if (e >= NE) return;
    int j = adjsrc[e], i = dstid[e];
    int t = ts[i];
    float w = 0.0f;
    if (tsrc[e] <= t)
        w = (float)dinvh[(size_t)t * NN + j] * (float)dinvh[(size_t)t * NN + i];
    int2 p;
    p.x = j;
    p.y = __float_as_int(w);
    ewp[e] = p;
}

// ---------------- counting sort of nodes by time bucket (no global atomics) ----------------
__global__ __launch_bounds__(256) void hist_rank(const int* __restrict__ ts,
                                                 int* __restrict__ cnt, int* __restrict__ rank) {
    __shared__ int h[TT];
    int tid = threadIdx.x, b = blockIdx.x;
    if (tid < TT) h[tid] = 0;
    __syncthreads();
    int i = b * 256 + tid;
    if (i < NN) {
        int t = ts[i];
        rank[i] = atomicAdd(&h[t], 1);   // LDS atomic: cheap
    }
    __syncthreads();
    if (tid < TT) cnt[b * TT + tid] = h[tid];
}

__global__ __launch_bounds__(256) void bucket_scan(const int* __restrict__ cnt,
                                                   int* __restrict__ basecol, int* __restrict__ bcnt) {
    __shared__ int s[256];
    int t = blockIdx.x, tid = threadIdx.x;
    const int CH = (HB + 255) / 256; // 4
    int b0 = tid * CH;
    int loc[CH];
    int sum = 0;
    for (int u = 0; u < CH; ++u) {
        int b = b0 + u;
        int v = (b < HB) ? cnt[b * TT + t] : 0;
        loc[u] = sum;
        sum += v;
    }
    s[tid] = sum;
    __syncthreads();
    for (int d = 1; d < 256; d <<= 1) {
        int u = (tid >= d) ? s[tid - d] : 0;
        __syncthreads();
        s[tid] += u;
        __syncthreads();
    }
    int base = s[tid] - sum;   // exclusive prefix for this thread's chunk
    for (int u = 0; u < CH; ++u) {
        int b = b0 + u;
        if (b < HB) basecol[b * TT + t] = base + loc[u];
    }
    if (tid == 255) bcnt[t] = s[255];
}

__global__ __launch_bounds__(256) void perm_scatter(const int* __restrict__ ts, const int* __restrict__ rank,
                                                    const int* __restrict__ basecol, const int* __restrict__ pstart,
                                                    int* __restrict__ perm) {
    int b = blockIdx.x;
    int i = b * 256 + threadIdx.x;
    if (i < NN) {
        int t = ts[i];
        perm[pstart[t] + basecol[b * TT + t] + rank[i]] = i;
    }
}

// ---------------- bucket / tile tables (32-row tiles) ----------------
__global__ void make_tiles(const int* __restrict__ bcnt, int* __restrict__ pstart,
                           int* __restrict__ tile_t, int* __restrict__ tile_r0,
                           int* __restrict__ meta) {
    __shared__ int s_nt[64];
    int t = threadIdx.x; // 64 threads
    int nt = (t < TT) ? (bcnt[t] + 31) / 32 : 0;
    s_nt[t] = nt;
    __syncthreads();
    for (int d = 1; d < 64; d <<= 1) {
        int v = (t >= d) ? s_nt[t - d] : 0;
        __syncthreads();
        s_nt[t] += v;
        __syncthreads();
    }
    int ntbase = s_nt[t] - nt;
    int pbase = ntbase * 32;
    if (t < TT) {
        pstart[t] = pbase;
        for (int u = 0; u < nt; ++u) {
            tile_t[ntbase + u] = t;
            tile_r0[ntbase + u] = pbase + u * 32;
        }
    }
    if (t == 63) {
        meta[0] = s_nt[63];
        meta[1] = s_nt[63] * 32;
        pstart[TT] = s_nt[63] * 32;
    }
}

// ---------------- GRU chain: 1 row/block, weights REGISTER-RESIDENT (2 cols/thread) ----------------
__global__ __launch_bounds__(512) void gru_evolve(
        const float* __restrict__ initial_w,
        const _Float16* __restrict__ wkp,      // [2][KP][512] half2
        const float* __restrict__ bih, const float* __restrict__ bhh,
        float* __restrict__ W_all) {
    __shared__ float s_w[FF];
    __shared__ __align__(16) _Float16 s_wh[2 * KP];   // 168 halfs = 21 f16x8 chunks
    __shared__ float s_pre[2][512];
    int tid = threadIdx.x;
    int row = blockIdx.x;

    if (tid < FF) {
        float v = initial_w[(size_t)row * FF + tid];
        s_w[tid] = v;
        s_wh[tid] = (_Float16)v;
    } else if (tid < 2 * KP) {
        s_wh[tid] = (_Float16)0.0f;
    }

    int cc0 = tid * 2;
    bool act = cc0 < 996;
    int m = (cc0 >= 498) ? 1 : 0;
    int c0 = act ? (cc0 - m * 498) : 0;

    half2v wr0[KP], wr1[KP];
    {
        const half2v* __restrict__ pW =
            (const half2v*)wkp + (size_t)(act ? m : 0) * (KP * 512) + c0;
        #pragma unroll
        for (int kp = 0; kp < KP; ++kp) {
            wr0[kp] = pW[(size_t)(kp << 9)];
            wr1[kp] = pW[(size_t)(kp << 9) + 1];
        }
    }

    float bi_r = 0, bi_z = 0, bi_n = 0, bh_r = 0, bh_z = 0, bh_n = 0;
    if (tid < FF) {
        bi_r = bih[tid]; bi_z = bih[FF + tid]; bi_n = bih[2 * FF + tid];
        bh_r = bhh[tid]; bh_z = bhh[FF + tid]; bh_n = bhh[2 * FF + tid];
    }
    __syncthreads();

    const f16x8* s_wh8 = (const f16x8*)s_wh;   // 21 chunks
    for (int t = 0; t < TT; ++t) {
        if (act) {
            float a0 = 0.0f, a1 = 0.0f;
            #pragma unroll
            for (int q = 0; q < 21; ++q) {
                f16x8 w8 = s_wh8[q];     // broadcast ds_read_b128
                half2v h0 = __builtin_shufflevector(w8, w8, 0, 1);
                half2v h1 = __builtin_shufflevector(w8, w8, 2, 3);
                half2v h2 = __builtin_shufflevector(w8, w8, 4, 5);
                half2v h3 = __builtin_shufflevector(w8, w8, 6, 7);
                a0 = fdot2f(wr0[4 * q + 0], h0, a0);  a1 = fdot2f(wr1[4 * q + 0], h0, a1);
                a0 = fdot2f(wr0[4 * q + 1], h1, a0);  a1 = fdot2f(wr1[4 * q + 1], h1, a1);
                a0 = fdot2f(wr0[4 * q + 2], h2, a0);  a1 = fdot2f(wr1[4 * q + 2], h2, a1);
                a0 = fdot2f(wr0[4 * q + 3], h3, a0);  a1 = fdot2f(wr1[4 * q + 3], h3, a1);
            }
            s_pre[m][c0]     = a0;
            s_pre[m][c0 + 1] = a1;
        }
        __syncthreads();
        if (tid < FF) {
            float i_r = s_pre[0][tid]          + bi_r;
            float h_r = s_pre[1][tid]          + bh_r;
            float i_z = s_pre[0][FF + tid]     + bi_z;
            float h_z = s_pre[1][FF + tid]     + bh_z;
            float i_n = s_pre[0][2 * FF + tid] + bi_n;
            float h_n = s_pre[1][2 * FF + tid] + bh_n;
            float rg = 1.0f / (1.0f + expf(-(i_r + h_r)));
            float zg = 1.0f / (1.0f + expf(-(i_z + h_z)));
            float ng = tanhf(i_n + rg * h_n);
            float wnew = (1.0f - zg) * ng + zg * s_w[tid];
            s_w[tid] = wnew;
            s_wh[tid] = (_Float16)wnew;
            W_all[((size_t)t * FF + row) * FF + tid] = wnew;
        }
        __syncthreads();
    }
}

// ---------------- Mh[t][h][k] (fp16, k padded to 192) = W_t @ projw^T transposed ----------------
__global__ __launch_bounds__(1024) void m_build(const float* __restrict__ W_all,
                                                const float* __restrict__ projwT,
                                                _Float16* __restrict__ Mh) {
    __shared__ __align__(16) float sw[8][168];
    int blk = blockIdx.x;
    int t = blk / 24, rb = blk - t * 24;
    int tid = threadIdx.x;
    int r0 = rb * 8;
    for (int idx = tid; idx < 8 * FF; idx += 1024) {
        int rr = idx / FF, k = idx - rr * FF;
        int r = r0 + rr;
        sw[rr][k] = (r < FF) ? W_all[((size_t)t * FF + r) * FF + k] : 0.0f;
    }
    __syncthreads();
    int rr = tid >> 7, h = tid & 127;
    int r = r0 + rr;
    if (r >= KPAD) return;
    float acc = 0.0f;
    if (r < FF) {
        const float* __restrict__ pw = projwT + h;
        #pragma unroll 4
        for (int c4 = 0; c4 < 164; c4 += 4) {
            float4 w = *(const float4*)&sw[rr][c4];
            acc += w.x * pw[(size_t)(c4 + 0) << 7];
            acc += w.y * pw[(size_t)(c4 + 1) << 7];
            acc += w.z * pw[(size_t)(c4 + 2) << 7];
            acc += w.w * pw[(size_t)(c4 + 3) << 7];
        }
        acc += sw[rr][164] * pw[(size_t)164 << 7];
        acc += sw[rr][165] * pw[(size_t)165 << 7];
    }
    Mh[((size_t)t * HH + h) * KPAD + r] = (_Float16)acc;
}

// ---------------- fused: 4-row-interleaved gather-aggregate into LDS, then MFMA + proj + cls ----------------
__global__ __launch_bounds__(512) void gemm_fused3(
        const int* __restrict__ meta, const int* __restrict__ tile_t,
        const int* __restrict__ tile_r0, const int* __restrict__ perm,
        const float* __restrict__ selfdeg, const half2v* __restrict__ x2,
        const int* __restrict__ off, const int2* __restrict__ ewp,
        const _Float16* __restrict__ Mh, const float* __restrict__ proj_b,
        const float* __restrict__ cls_w, const float* __restrict__ cls_b,
        float* __restrict__ out) {
    __shared__ __align__(16) char smraw[32 * 130 * 4];   // 16640 B (sY needs 12800)
    _Float16* sY = (_Float16*)smraw;   // [32][200] fp16
    float* sP = (float*)smraw;         // [32][130] f32
    int bid = blockIdx.x;
    if (bid >= meta[0]) return;
    int t = tile_t[bid], r0 = tile_r0[bid];
    int tid = threadIdx.x;
    int lane = tid & 63;
    int w = tid >> 6;          // 8 waves
    bool lo = lane < 32;

    // ---- phase 0: aggregation, 4 rows per wave processed CONCURRENTLY ----
    int rbase = w * 4;
    int idx4[4], ep[4], ee[4];
    float ax[4], ay[4], bx[4], by[4];
    #pragma unroll
    for (int q = 0; q < 4; ++q) {
        int i = perm[r0 + rbase + q];
        idx4[q] = i;
        ax[q] = ay[q] = bx[q] = by[q] = 0.0f;
        ep[q] = 0; ee[q] = 0;
        if (i >= 0) { ep[q] = off[i]; ee[q] = off[i + 1]; }
    }
    // self terms: 4 independent gathers in flight
    #pragma unroll
    for (int q = 0; q < 4; ++q) {
        int i = idx4[q];
        if (i >= 0) {
            float sw = selfdeg[i];
            const half2v* xi = x2 + (size_t)i * 96;
            half2v h0 = xi[lane];
            ax[q] = sw * (float)h0[0];
            ay[q] = sw * (float)h0[1];
            if (lo) {
                half2v h1 = xi[64 + lane];
                bx[q] = sw * (float)h1[0];
                by[q] = sw * (float)h1[1];
            }
        }
    }
    // interleaved edge loop: per iteration, up to 4 independent ewp loads + 4 row gathers
    while ((ep[0] < ee[0]) | (ep[1] < ee[1]) | (ep[2] < ee[2]) | (ep[3] < ee[3])) {
        float wv[4]; int js[4];
        #pragma unroll
        for (int q = 0; q < 4; ++q) {
            wv[q] = 0.0f; js[q] = 0;
            if (ep[q] < ee[q]) {
                int2 p = ewp[ep[q]++];
                js[q] = p.x;
                wv[q] = __int_as_float(p.y);
            }
        }
        #pragma unroll
        for (int q = 0; q < 4; ++q) {
            if (wv[q] != 0.0f) {
                const half2v* xj = x2 + (size_t)js[q] * 96;
                half2v g0 = xj[lane];
                ax[q] += wv[q] * (float)g0[0];
                ay[q] += wv[q] * (float)g0[1];
                if (lo) {
                    half2v g1 = xj[64 + lane];
                    bx[q] += wv[q] * (float)g1[0];
                    by[q] += wv[q] * (float)g1[1];
                }
            }
        }
    }
    #pragma unroll
    for (int q = 0; q < 4; ++q) {
        half2v o0;
        o0[0] = (_Float16)ax[q];
        o0[1] = (_Float16)ay[q];
        *(half2v*)(sY + (rbase + q) * 200 + lane * 2) = o0;
        if (lo) {
            half2v o1;
            o1[0] = (_Float16)bx[q];
            o1[1] = (_Float16)by[q];
            *(half2v*)(sY + (rbase + q) * 200 + 128 + lane * 2) = o1;
        }
    }
    __syncthreads();

    // ---- phase 1: MFMA. wave w -> 16-col block c0 = w*16
    int lr = lane & 15;
    int kg = lane >> 4;
    int c0 = w * 16;
    f32x4 acc0 = {0, 0, 0, 0}, acc1 = {0, 0, 0, 0};
    const _Float16* B0 = Mh + ((size_t)t * HH + c0 + lr) * KPAD + kg * 8;
    const _Float16* A0 = sY + lr * 200 + kg * 8;
    const _Float16* A1 = A0 + 16 * 200;

    #pragma unroll
    for (int s = 0; s < 6; ++s) {
        f16x8 b0 = *(const f16x8*)(B0 + s * 32);
        f16x8 a0 = *(const f16x8*)(A0 + s * 32);
        f16x8 a1 = *(const f16x8*)(A1 + s * 32);
        acc0 = __builtin_amdgcn_mfma_f32_16x16x32_f16(a0, b0, acc0, 0, 0, 0);
        acc1 = __builtin_amdgcn_mfma_f32_16x16x32_f16(a1, b0, acc1, 0, 0, 0);
    }

    float pb = proj_b[c0 + lr];
    __syncthreads();   // LDS reads done; reuse as sP
    int prow = kg * 4;
    int colw = c0 + lr;
    #pragma unroll
    for (int r = 0; r < 4; ++r) {
        sP[(prow + r) * 130 + colw]      = fmaxf(acc0[r] + pb, 0.0f);
        sP[(16 + prow + r) * 130 + colw] = fmaxf(acc1[r] + pb, 0.0f);
    }
    __syncthreads();

    // ---- phase 2: logits. tid -> row(32) x cc(2) x chunk(8)
    int row = tid >> 4, cc = (tid >> 3) & 1, qq = tid & 7;
    const float* pr = sP + row * 130 + qq * 16;
    const float* cw = cls_w + cc * HH + qq * 16;
    float s = 0.0f;
    #pragma unroll
    for (int h = 0; h < 16; ++h) s += pr[h] * cw[h];
    s += __shfl_xor(s, 1);
    s += __shfl_xor(s, 2);
    s += __shfl_xor(s, 4);
    if (qq == 0) {
        int node = perm[r0 + row];
        if (node >= 0) out[(size_t)node * CC + cc] = s + cls_b[cc];
    }
}

// ---------------- host ----------------
extern "C" void kernel_launch(void* const* d_in, const int* in_sizes, int n_in,
                              void* d_out, int out_size, void* d_ws, size_t ws_size,
                              hipStream_t stream) {
    const float* x = (const float*)d_in[0];
    const int* ei = (const int*)d_in[1];
    const int* srcp = ei;
    const int* dstp = ei + NE;
    const int* ts = (const int*)d_in[2];
    const float* initial_w = (const float*)d_in[3];
    const float* wih = (const float*)d_in[4];
    const float* whh = (const float*)d_in[5];
    const float* bih = (const float*)d_in[6];
    const float* bhh = (const float*)d_in[7];
    const float* projw = (const float*)d_in[8];
    const float* projb = (const float*)d_in[9];
    const float* clsw = (const float*)d_in[10];
    const float* clsb = (const float*)d_in[11];
    float* out = (float*)d_out;

    char* base = (char*)d_ws;
    size_t o = 0;
    auto alloc = [&](size_t bytes) { size_t r = o; o = (o + bytes + 255) & ~(size_t)255; return r; };

    float*    W_all   = (float*)   (base + alloc((size_t)TT * FF * FF * 4));
    _Float16* Mh      = (_Float16*)(base + alloc((size_t)TT * HH * KPAD * 2));
    _Float16* wkp     = (_Float16*)(base + alloc((size_t)2 * KP * 512 * 2 * 2));
    float*    projwT  = (float*)   (base + alloc((size_t)FF * HH * 4));
    int*      off     = (int*)     (base + alloc((size_t)(NN + 1) * 4));
    int*      cursor  = (int*)     (base + alloc((size_t)NN * 4));
    int*      adjsrc  = (int*)     (base + alloc((size_t)NE * 4));
    int*      dstid   = (int*)     (base + alloc((size_t)NE * 4));
    int*      tsrc    = (int*)     (base + alloc((size_t)NE * 4));
    int2*     ewp     = (int2*)    (base + alloc((size_t)NE * 8));
    _Float16* dinvh   = (_Float16*)(base + alloc((size_t)TT * NN * 2));
    float*    selfdeg = (float*)   (base + alloc((size_t)NN * 4));
    int*      bcnt    = (int*)     (base + alloc((size_t)TT * 4));
    int*      pstart  = (int*)     (base + alloc((size_t)(TT + 1) * 4));
    int*      meta    = (int*)     (base + alloc(2 * 4));
    int*      tile_t  = (int*)     (base + alloc((size_t)MAXTILES * 4));
    int*      tile_r0 = (int*)     (base + alloc((size_t)MAXTILES * 4));
    int*      perm    = (int*)     (base + alloc((size_t)PADN * 4));
    int*      bsum    = (int*)     (base + alloc((size_t)512 * 4));
    int*      bpre    = (int*)     (base + alloc((size_t)520 * 4));
    int*      cnt     = (int*)     (base + alloc((size_t)HB * TT * 4));
    int*      basecol = (int*)     (base + alloc((size_t)HB * TT * 4));
    int*      rank    = (int*)     (base + alloc((size_t)NN * 4));
    half2v*   x2      = (half2v*)  (base + alloc((size_t)NN * 96 * 4));

    hipMemsetAsync(off, 0, (size_t)(NN + 1) * 4, stream);
    hipMemsetAsync(cursor, 0, (size_t)NN * 4, stream);
    hipMemsetAsync(perm, 0xFF, (size_t)PADN * 4, stream);

    prep_pack<<<420, 256, 0, stream>>>(wih, whh, projw, wkp, projwT);
    x_to_h<<<(NN * 96 + 255) / 256, 256, 0, stream>>>(x, x2);
    count_indeg<<<(NE + 255) / 256, 256, 0, stream>>>(dstp, off);
    hist_rank<<<HB, 256, 0, stream>>>(ts, cnt, rank);
    scan_p1<<<SNB, 256, 0, stream>>>(off, bsum);
    scan_p2<<<1, 512, 0, stream>>>(bsum, bpre, off);
    scan_p3<<<SNB, 512, 0, stream>>>(off, bpre);
    fill_adj<<<(NE + 255) / 256, 256, 0, stream>>>(srcp, dstp, ts, off, cursor, adjsrc, dstid, tsrc);
    degf_hist<<<(NN + 255) / 256, 256, 0, stream>>>(off, tsrc, ts, dinvh, selfdeg);
    edge_prep<<<(NE + 255) / 256, 256, 0, stream>>>(adjsrc, dstid, tsrc, ts, dinvh, ewp);
    bucket_scan<<<TT, 256, 0, stream>>>(cnt, basecol, bcnt);
    make_tiles<<<1, 64, 0, stream>>>(bcnt, pstart, tile_t, tile_r0, meta);
    perm_scatter<<<HB, 256, 0, stream>>>(ts, rank, basecol, pstart, perm);

    gru_evolve<<<FF, 512, 0, stream>>>(initial_w, wkp, bih, bhh, W_all);
    m_build<<<TT * 24, 1024, 0, stream>>>(W_all, projwT, Mh);

    gemm_fused3<<<MAXTILES, 512, 0, stream>>>(meta, tile_t, tile_r0, perm, selfdeg,
                                              x2, off, ewp, Mh, projb, clsw, clsb, out);
}

// Round 11
// 379.248 us; speedup vs baseline: 1.4782x; 1.0311x over previous
//
#include <hip/hip_runtime.h>
#include <hip/hip_fp16.h>
#include <math.h>

#define NN 200000
#define NE 500000
#define FF 166
#define HH 128
#define CC 2
#define TT 49
#define GG 498            // 3*FF
#define PADN 203136
#define MAXTILES 6400
#define KP 84             // k-pairs (166 -> 84 half2, padded)
#define KPAD 192          // K padded to 6*32 for MFMA
#define SCB 512           // scan elements per block
#define SNB 391           // ceil(NN/512)
#define HB 782            // ceil(NN/256) histogram blocks

typedef _Float16 half2v __attribute__((ext_vector_type(2)));
typedef _Float16 f16x8 __attribute__((ext_vector_type(8)));
typedef float f32x4 __attribute__((ext_vector_type(4)));

static __device__ __forceinline__ float fdot2f(half2v a, half2v b, float c) {
#if __has_builtin(__builtin_amdgcn_fdot2)
    return __builtin_amdgcn_fdot2(a, b, c, false);
#else
    return c + (float)a.x * (float)b.x + (float)a.y * (float)b.y;
#endif
}

// ---------------- prep: pack GRU weights as [m][kp][512] half2 (k-pairs), fp32 projT ----------------
__global__ void prep_pack(const float* __restrict__ wih, const float* __restrict__ whh,
                          const float* __restrict__ projw,
                          _Float16* __restrict__ wkp, float* __restrict__ projwT) {
    int idx = blockIdx.x * 256 + threadIdx.x;
    const int A = 2 * KP * 512; // 86016 half2 slots
    if (idx < A) {
        int m = idx / (KP * 512);
        int r = idx - m * (KP * 512);
        int kp = r >> 9, c = r & 511;
        const float* Wm = m ? whh : wih;
        float x0 = 0.0f, x1 = 0.0f;
        if (c < GG) {
            int k0 = 2 * kp, k1 = 2 * kp + 1;
            if (k0 < FF) x0 = Wm[c * FF + k0];
            if (k1 < FF) x1 = Wm[c * FF + k1];
        }
        wkp[2 * idx]     = (_Float16)x0;
        wkp[2 * idx + 1] = (_Float16)x1;
    } else if (idx < A + FF * HH) {
        int q = idx - A;
        int k = q >> 7, h = q & 127;
        projwT[q] = projw[h * FF + k];
    }
}

// ---------------- x -> fp16, scattered into PERM order: x2p[pos[i]] = x[i] ----------------
__global__ __launch_bounds__(256) void x_scatter_h(const float* __restrict__ x,
                                                   const int* __restrict__ pos,
                                                   half2v* __restrict__ x2p) {
    int idx = blockIdx.x * 256 + threadIdx.x;
    if (idx >= NN * 96) return;
    int i = idx / 96, cp = idx - i * 96;
    int c0 = cp * 2;
    float v0 = (c0 < FF) ? x[(size_t)i * FF + c0] : 0.0f;
    float v1 = (c0 + 1 < FF) ? x[(size_t)i * FF + c0 + 1] : 0.0f;
    half2v h;
    h[0] = (_Float16)v0;
    h[1] = (_Float16)v1;
    x2p[(size_t)pos[i] * 96 + cp] = h;
}

// ---------------- CSR build ----------------
__global__ void count_indeg(const int* __restrict__ dst, int* __restrict__ off) {
    int e = blockIdx.x * 256 + threadIdx.x;
    if (e < NE) atomicAdd(&off[dst[e]], 1);
}

// ---- 3-phase multi-block exclusive scan of off[0..NN) ----
__global__ __launch_bounds__(256) void scan_p1(const int* __restrict__ off, int* __restrict__ bsum) {
    __shared__ int s[256];
    int b = blockIdx.x, tid = threadIdx.x;
    int i0 = b * SCB + tid * 2;
    int v = 0;
    if (i0 < NN) v += off[i0];
    if (i0 + 1 < NN) v += off[i0 + 1];
    s[tid] = v;
    __syncthreads();
    for (int d = 128; d > 0; d >>= 1) {
        if (tid < d) s[tid] += s[tid + d];
        __syncthreads();
    }
    if (tid == 0) bsum[b] = s[0];
}

__global__ __launch_bounds__(512) void scan_p2(const int* __restrict__ bsum, int* __restrict__ bpre,
                                               int* __restrict__ off) {
    __shared__ int s[512];
    int tid = threadIdx.x;
    int v = (tid < SNB) ? bsum[tid] : 0;
    s[tid] = v;
    __syncthreads();
    for (int d = 1; d < 512; d <<= 1) {
        int u = (tid >= d) ? s[tid - d] : 0;
        __syncthreads();
        s[tid] += u;
        __syncthreads();
    }
    bpre[tid] = s[tid] - v;  // exclusive
    if (tid == 511) off[NN] = s[511];
}

__global__ __launch_bounds__(512) void scan_p3(int* __restrict__ off, const int* __restrict__ bpre) {
    __shared__ int s[512];
    int b = blockIdx.x, tid = threadIdx.x;
    int i = b * SCB + tid;
    int v = (i < NN) ? off[i] : 0;
    s[tid] = v;
    __syncthreads();
    for (int d = 1; d < 512; d <<= 1) {
        int u = (tid >= d) ? s[tid - d] : 0;
        __syncthreads();
        s[tid] += u;
        __syncthreads();
    }
    if (i < NN) off[i] = s[tid] - v + bpre[b];
}

__global__ void fill_adj(const int* __restrict__ src, const int* __restrict__ dst,
                         const int* __restrict__ ts,
                         const int* __restrict__ off, int* __restrict__ cursor,
                         int* __restrict__ adjsrc, int* __restrict__ tsrc) {
    int e = blockIdx.x * 256 + threadIdx.x;
    if (e < NE) {
        int d = dst[e];
        int s = src[e];
        int p = atomicAdd(&cursor[d], 1);
        int pos = off[d] + p;
        adjsrc[pos] = s;
        tsrc[pos] = ts[s];
    }
}

// dinvh[t][i] = rsqrt(deg); selfdeg[i] = exact 1/deg at t=ts[i]
__global__ __launch_bounds__(256) void degf_hist(const int* __restrict__ off, const int* __restrict__ tsrc,
                                                 const int* __restrict__ ts, _Float16* __restrict__ dinvh,
                                                 float* __restrict__ selfdeg) {
    __shared__ unsigned short sh[TT * 256];
    int tid = threadIdx.x;
    int i = blockIdx.x * 256 + tid;
    for (int t = 0; t < TT; ++t) sh[t * 256 + tid] = 0;
    if (i >= NN) return;
    int tsi = ts[i];
    int e0 = off[i], e1 = off[i + 1];
    for (int e = e0; e < e1; ++e) {
        int tj = tsrc[e];
        sh[tj * 256 + tid]++;
    }
    int cum = 1;
    for (int t = 0; t < TT; ++t) {
        cum += sh[t * 256 + tid];
        dinvh[(size_t)t * NN + i] = (_Float16)rsqrtf((float)cum);
        if (t == tsi) selfdeg[i] = 1.0f / (float)cum;
    }
}

// ---------------- node-parallel ACTIVE edge compaction: ewp[off[i]..] = {pos[j], w>0} ----------------
__global__ __launch_bounds__(256) void edge_compact(
        const int* __restrict__ off, const int* __restrict__ adjsrc, const int* __restrict__ tsrc,
        const int* __restrict__ ts, const _Float16* __restrict__ dinvh, const int* __restrict__ pos,
        int2* __restrict__ ewp, int* __restrict__ nact) {
    int i = blockIdx.x * 256 + threadIdx.x;
    if (i >= NN) return;
    int t = ts[i];
    const _Float16* dv = dinvh + (size_t)t * NN;
    float dvi = (float)dv[i];
    int e0 = off[i], e1 = off[i + 1];
    int c = e0;
    for (int e = e0; e < e1; ++e) {
        if (tsrc[e] <= t) {
            int j = adjsrc[e];
            float w = (float)dv[j] * dvi;
            int2 p;
            p.x = pos[j];
            p.y = __float_as_int(w);
            ewp[c++] = p;
        }
    }
    nact[i] = c - e0;
}

// ---------------- counting sort of nodes by time bucket ----------------
__global__ __launch_bounds__(256) void hist_rank(const int* __restrict__ ts,
                                                 int* __restrict__ cnt, int* __restrict__ rank) {
    __shared__ int h[TT];
    int tid = threadIdx.x, b = blockIdx.x;
    if (tid < TT) h[tid] = 0;
    __syncthreads();
    int i = b * 256 + tid;
    if (i < NN) {
        int t = ts[i];
        rank[i] = atomicAdd(&h[t], 1);
    }
    __syncthreads();
    if (tid < TT) cnt[b * TT + tid] = h[tid];
}

__global__ __launch_bounds__(256) void bucket_scan(const int* __restrict__ cnt,
                                                   int* __restrict__ basecol, int* __restrict__ bcnt) {
    __shared__ int s[256];
    int t = blockIdx.x, tid = threadIdx.x;
    const int CH = (HB + 255) / 256; // 4
    int b0 = tid * CH;
    int loc[CH];
    int sum = 0;
    for (int u = 0; u < CH; ++u) {
        int b = b0 + u;
        int v = (b < HB) ? cnt[b * TT + t] : 0;
        loc[u] = sum;
        sum += v;
    }
    s[tid] = sum;
    __syncthreads();
    for (int d = 1; d < 256; d <<= 1) {
        int u = (tid >= d) ? s[tid - d] : 0;
        __syncthreads();
        s[tid] += u;
        __syncthreads();
    }
    int base = s[tid] - sum;
    for (int u = 0; u < CH; ++u) {
        int b = b0 + u;
        if (b < HB) basecol[b * TT + t] = base + loc[u];
    }
    if (tid == 255) bcnt[t] = s[255];
}

__global__ __launch_bounds__(256) void perm_scatter(const int* __restrict__ ts, const int* __restrict__ rank,
                                                    const int* __restrict__ basecol, const int* __restrict__ pstart,
                                                    int* __restrict__ perm, int* __restrict__ pos) {
    int b = blockIdx.x;
    int i = b * 256 + threadIdx.x;
    if (i < NN) {
        int t = ts[i];
        int p = pstart[t] + basecol[b * TT + t] + rank[i];
        perm[p] = i;
        pos[i] = p;
    }
}

// ---------------- bucket / tile tables (32-row tiles) ----------------
__global__ void make_tiles(const int* __restrict__ bcnt, int* __restrict__ pstart,
                           int* __restrict__ tile_t, int* __restrict__ tile_r0,
                           int* __restrict__ meta) {
    __shared__ int s_nt[64];
    int t = threadIdx.x;
    int nt = (t < TT) ? (bcnt[t] + 31) / 32 : 0;
    s_nt[t] = nt;
    __syncthreads();
    for (int d = 1; d < 64; d <<= 1) {
        int v = (t >= d) ? s_nt[t - d] : 0;
        __syncthreads();
        s_nt[t] += v;
        __syncthreads();
    }
    int ntbase = s_nt[t] - nt;
    int pbase = ntbase * 32;
    if (t < TT) {
        pstart[t] = pbase;
        for (int u = 0; u < nt; ++u) {
            tile_t[ntbase + u] = t;
            tile_r0[ntbase + u] = pbase + u * 32;
        }
    }
    if (t == 63) {
        meta[0] = s_nt[63];
        meta[1] = s_nt[63] * 32;
        pstart[TT] = s_nt[63] * 32;
    }
}

// ---------------- GRU chain: 1 row/block, weights REGISTER-RESIDENT (2 cols/thread) ----------------
__global__ __launch_bounds__(512) void gru_evolve(
        const float* __restrict__ initial_w,
        const _Float16* __restrict__ wkp,      // [2][KP][512] half2
        const float* __restrict__ bih, const float* __restrict__ bhh,
        float* __restrict__ W_all) {
    __shared__ float s_w[FF];
    __shared__ __align__(16) _Float16 s_wh[2 * KP];
    __shared__ float s_pre[2][512];
    int tid = threadIdx.x;
    int row = blockIdx.x;

    if (tid < FF) {
        float v = initial_w[(size_t)row * FF + tid];
        s_w[tid] = v;
        s_wh[tid] = (_Float16)v;
    } else if (tid < 2 * KP) {
        s_wh[tid] = (_Float16)0.0f;
    }

    int cc0 = tid * 2;
    bool act = cc0 < 996;
    int m = (cc0 >= 498) ? 1 : 0;
    int c0 = act ? (cc0 - m * 498) : 0;

    half2v wr0[KP], wr1[KP];
    {
        const half2v* __restrict__ pW =
            (const half2v*)wkp + (size_t)(act ? m : 0) * (KP * 512) + c0;
        #pragma unroll
        for (int kp = 0; kp < KP; ++kp) {
            wr0[kp] = pW[(size_t)(kp << 9)];
            wr1[kp] = pW[(size_t)(kp << 9) + 1];
        }
    }

    float bi_r = 0, bi_z = 0, bi_n = 0, bh_r = 0, bh_z = 0, bh_n = 0;
    if (tid < FF) {
        bi_r = bih[tid]; bi_z = bih[FF + tid]; bi_n = bih[2 * FF + tid];
        bh_r = bhh[tid]; bh_z = bhh[FF + tid]; bh_n = bhh[2 * FF + tid];
    }
    __syncthreads();

    const f16x8* s_wh8 = (const f16x8*)s_wh;
    for (int t = 0; t < TT; ++t) {
        if (act) {
            float a0 = 0.0f, a1 = 0.0f;
            #pragma unroll
            for (int q = 0; q < 21; ++q) {
                f16x8 w8 = s_wh8[q];
                half2v h0 = __builtin_shufflevector(w8, w8, 0, 1);
                half2v h1 = __builtin_shufflevector(w8, w8, 2, 3);
                half2v h2 = __builtin_shufflevector(w8, w8, 4, 5);
                half2v h3 = __builtin_shufflevector(w8, w8, 6, 7);
                a0 = fdot2f(wr0[4 * q + 0], h0, a0);  a1 = fdot2f(wr1[4 * q + 0], h0, a1);
                a0 = fdot2f(wr0[4 * q + 1], h1, a0);  a1 = fdot2f(wr1[4 * q + 1], h1, a1);
                a0 = fdot2f(wr0[4 * q + 2], h2, a0);  a1 = fdot2f(wr1[4 * q + 2], h2, a1);
                a0 = fdot2f(wr0[4 * q + 3], h3, a0);  a1 = fdot2f(wr1[4 * q + 3], h3, a1);
            }
            s_pre[m][c0]     = a0;
            s_pre[m][c0 + 1] = a1;
        }
        __syncthreads();
        if (tid < FF) {
            float i_r = s_pre[0][tid]          + bi_r;
            float h_r = s_pre[1][tid]          + bh_r;
            float i_z = s_pre[0][FF + tid]     + bi_z;
            float h_z = s_pre[1][FF + tid]     + bh_z;
            float i_n = s_pre[0][2 * FF + tid] + bi_n;
            float h_n = s_pre[1][2 * FF + tid] + bh_n;
            float rg = 1.0f / (1.0f + expf(-(i_r + h_r)));
            float zg = 1.0f / (1.0f + expf(-(i_z + h_z)));
            float ng = tanhf(i_n + rg * h_n);
            float wnew = (1.0f - zg) * ng + zg * s_w[tid];
            s_w[tid] = wnew;
            s_wh[tid] = (_Float16)wnew;
            W_all[((size_t)t * FF + row) * FF + tid] = wnew;
        }
        __syncthreads();
    }
}

// ---------------- Mh[t][h][k] (fp16, k padded to 192) = W_t @ projw^T transposed ----------------
__global__ __launch_bounds__(1024) void m_build(const float* __restrict__ W_all,
                                                const float* __restrict__ projwT,
                                                _Float16* __restrict__ Mh) {
    __shared__ __align__(16) float sw[8][168];
    int blk = blockIdx.x;
    int t = blk / 24, rb = blk - t * 24;
    int tid = threadIdx.x;
    int r0 = rb * 8;
    for (int idx = tid; idx < 8 * FF; idx += 1024) {
        int rr = idx / FF, k = idx - rr * FF;
        int r = r0 + rr;
        sw[rr][k] = (r < FF) ? W_all[((size_t)t * FF + r) * FF + k] : 0.0f;
    }
    __syncthreads();
    int rr = tid >> 7, h = tid & 127;
    int r = r0 + rr;
    if (r >= KPAD) return;
    float acc = 0.0f;
    if (r < FF) {
        const float* __restrict__ pw = projwT + h;
        #pragma unroll 4
        for (int c4 = 0; c4 < 164; c4 += 4) {
            float4 w = *(const float4*)&sw[rr][c4];
            acc += w.x * pw[(size_t)(c4 + 0) << 7];
            acc += w.y * pw[(size_t)(c4 + 1) << 7];
            acc += w.z * pw[(size_t)(c4 + 2) << 7];
            acc += w.w * pw[(size_t)(c4 + 3) << 7];
        }
        acc += sw[rr][164] * pw[(size_t)164 << 7];
        acc += sw[rr][165] * pw[(size_t)165 << 7];
    }
    Mh[((size_t)t * HH + h) * KPAD + r] = (_Float16)acc;
}

// ---------------- fused: seq-staged self + compacted-edge gather, then MFMA + proj + cls ----------------
__global__ __launch_bounds__(512) void gemm_fused4(
        const int* __restrict__ meta, const int* __restrict__ tile_t,
        const int* __restrict__ tile_r0, const int* __restrict__ perm,
        const float* __restrict__ selfdeg, const half2v* __restrict__ x2p,
        const int* __restrict__ off, const int* __restrict__ nact,
        const int2* __restrict__ ewp,
        const _Float16* __restrict__ Mh, const float* __restrict__ proj_b,
        const float* __restrict__ cls_w, const float* __restrict__ cls_b,
        float* __restrict__ out) {
    __shared__ __align__(16) char smraw[32 * 130 * 4];
    _Float16* sY = (_Float16*)smraw;   // [32][200] fp16
    float* sP = (float*)smraw;         // [32][130] f32
    int bid = blockIdx.x;
    if (bid >= meta[0]) return;
    int t = tile_t[bid], r0 = tile_r0[bid];
    int tid = threadIdx.x;
    int lane = tid & 63;
    int w = tid >> 6;          // 8 waves
    bool lo = lane < 32;

    // ---- stage x2p tile (rows r0..r0+31, CONTIGUOUS: 32 x 24 uint4 = 12 KB) ----
    {
        const uint4* src = (const uint4*)(x2p + (size_t)r0 * 96);
        #pragma unroll
        for (int u = 0; u < 2; ++u) {
            int q = tid + u * 512;                // 0..767 (768 = 32*24)
            if (q < 768) {
                int row = q / 24, kc = q - row * 24;
                *(uint4*)(sY + row * 200 + kc * 8) = src[q];
            }
        }
    }
    __syncthreads();

    // ---- phase 0: per-wave 4-row aggregation; acc init from staged self-term ----
    int rbase = w * 4;
    int ep[4], ee[4];
    float ax[4], ay[4], bx[4], by[4];
    #pragma unroll
    for (int q = 0; q < 4; ++q) {
        int r = rbase + q;
        int i = perm[r0 + r];
        float sw = 0.0f;
        ep[q] = 0; ee[q] = 0;
        if (i >= 0) {
            sw = selfdeg[i];
            int e0 = off[i];
            ep[q] = e0;
            ee[q] = e0 + nact[i];
        }
        half2v h0 = *(const half2v*)(sY + r * 200 + lane * 2);
        ax[q] = sw * (float)h0[0];
        ay[q] = sw * (float)h0[1];
        bx[q] = 0.0f; by[q] = 0.0f;
        if (lo) {
            half2v h1 = *(const half2v*)(sY + r * 200 + 128 + lane * 2);
            bx[q] = sw * (float)h1[0];
            by[q] = sw * (float)h1[1];
        }
    }
    while ((ep[0] < ee[0]) | (ep[1] < ee[1]) | (ep[2] < ee[2]) | (ep[3] < ee[3])) {
        float wv[4]; int js[4];
        #pragma unroll
        for (int q = 0; q < 4; ++q) {
            wv[q] = 0.0f; js[q] = 0;
            if (ep[q] < ee[q]) {
                int2 p = ewp[ep[q]++];
                js[q] = p.x;                       // PERM-row index
                wv[q] = __int_as_float(p.y);
            }
        }
        #pragma unroll
        for (int q = 0; q < 4; ++q) {
            if (wv[q] != 0.0f) {
                const half2v* xj = x2p + (size_t)js[q] * 96;
                half2v g0 = xj[lane];
                ax[q] += wv[q] * (float)g0[0];
                ay[q] += wv[q] * (float)g0[1];
                if (lo) {
                    half2v g1 = xj[64 + lane];
                    bx[q] += wv[q] * (float)g1[0];
                    by[q] += wv[q] * (float)g1[1];
                }
            }
        }
    }
    __syncthreads();   // everyone done READING staged self values
    #pragma unroll
    for (int q = 0; q < 4; ++q) {
        half2v o0;
        o0[0] = (_Float16)ax[q];
        o0[1] = (_Float16)ay[q];
        *(half2v*)(sY + (rbase + q) * 200 + lane * 2) = o0;
        if (lo) {
            half2v o1;
            o1[0] = (_Float16)bx[q];
            o1[1] = (_Float16)by[q];
            *(half2v*)(sY + (rbase + q) * 200 + 128 + lane * 2) = o1;
        }
    }
    __syncthreads();

    // ---- phase 1: MFMA. wave w -> 16-col block c0 = w*16
    int lr = lane & 15;
    int kg = lane >> 4;
    int c0 = w * 16;
    f32x4 acc0 = {0, 0, 0, 0}, acc1 = {0, 0, 0, 0};
    const _Float16* B0 = Mh + ((size_t)t * HH + c0 + lr) * KPAD + kg * 8;
    const _Float16* A0 = sY + lr * 200 + kg * 8;
    const _Float16* A1 = A0 + 16 * 200;

    #pragma unroll
    for (int s = 0; s < 6; ++s) {
        f16x8 b0 = *(const f16x8*)(B0 + s * 32);
        f16x8 a0 = *(const f16x8*)(A0 + s * 32);
        f16x8 a1 = *(const f16x8*)(A1 + s * 32);
        acc0 = __builtin_amdgcn_mfma_f32_16x16x32_f16(a0, b0, acc0, 0, 0, 0);
        acc1 = __builtin_amdgcn_mfma_f32_16x16x32_f16(a1, b0, acc1, 0, 0, 0);
    }

    float pb = proj_b[c0 + lr];
    __syncthreads();
    int prow = kg * 4;
    int colw = c0 + lr;
    #pragma unroll
    for (int r = 0; r < 4; ++r) {
        sP[(prow + r) * 130 + colw]      = fmaxf(acc0[r] + pb, 0.0f);
        sP[(16 + prow + r) * 130 + colw] = fmaxf(acc1[r] + pb, 0.0f);
    }
    __syncthreads();

    // ---- phase 2: logits
    int row = tid >> 4, cc = (tid >> 3) & 1, qq = tid & 7;
    const float* pr = sP + row * 130 + qq * 16;
    const float* cw = cls_w + cc * HH + qq * 16;
    float s = 0.0f;
    #pragma unroll
    for (int h = 0; h < 16; ++h) s += pr[h] * cw[h];
    s += __shfl_xor(s, 1);
    s += __shfl_xor(s, 2);
    s += __shfl_xor(s, 4);
    if (qq == 0) {
        int node = perm[r0 + row];
        if (node >= 0) out[(size_t)node * CC + cc] = s + cls_b[cc];
    }
}

// ---------------- host ----------------
extern "C" void kernel_launch(void* const* d_in, const int* in_sizes, int n_in,
                              void* d_out, int out_size, void* d_ws, size_t ws_size,
                              hipStream_t stream) {
    const float* x = (const float*)d_in[0];
    const int* ei = (const int*)d_in[1];
    const int* srcp = ei;
    const int* dstp = ei + NE;
    const int* ts = (const int*)d_in[2];
    const float* initial_w = (const float*)d_in[3];
    const float* wih = (const float*)d_in[4];
    const float* whh = (const float*)d_in[5];
    const float* bih = (const float*)d_in[6];
    const float* bhh = (const float*)d_in[7];
    const float* projw = (const float*)d_in[8];
    const float* projb = (const float*)d_in[9];
    const float* clsw = (const float*)d_in[10];
    const float* clsb = (const float*)d_in[11];
    float* out = (float*)d_out;

    char* base = (char*)d_ws;
    size_t o = 0;
    auto alloc = [&](size_t bytes) { size_t r = o; o = (o + bytes + 255) & ~(size_t)255; return r; };

    float*    W_all   = (float*)   (base + alloc((size_t)TT * FF * FF * 4));
    _Float16* Mh      = (_Float16*)(base + alloc((size_t)TT * HH * KPAD * 2));
    _Float16* wkp     = (_Float16*)(base + alloc((size_t)2 * KP * 512 * 2 * 2));
    float*    projwT  = (float*)   (base + alloc((size_t)FF * HH * 4));
    int*      off     = (int*)     (base + alloc((size_t)(NN + 1) * 4));
    int*      cursor  = (int*)     (base + alloc((size_t)NN * 4));
    int*      adjsrc  = (int*)     (base + alloc((size_t)NE * 4));
    int*      tsrc    = (int*)     (base + alloc((size_t)NE * 4));
    int2*     ewp     = (int2*)    (base + alloc((size_t)NE * 8));
    _Float16* dinvh   = (_Float16*)(base + alloc((size_t)TT * NN * 2));
    float*    selfdeg = (float*)   (base + alloc((size_t)NN * 4));
    int*      nact    = (int*)     (base + alloc((size_t)NN * 4));
    int*      pos     = (int*)     (base + alloc((size_t)NN * 4));
    int*      bcnt    = (int*)     (base + alloc((size_t)TT * 4));
    int*      pstart  = (int*)     (base + alloc((size_t)(TT + 1) * 4));
    int*      meta    = (int*)     (base + alloc(2 * 4));
    int*      tile_t  = (int*)     (base + alloc((size_t)MAXTILES * 4));
    int*      tile_r0 = (int*)     (base + alloc((size_t)MAXTILES * 4));
    int*      perm    = (int*)     (base + alloc((size_t)PADN * 4));
    int*      bsum    = (int*)     (base + alloc((size_t)512 * 4));
    int*      bpre    = (int*)     (base + alloc((size_t)520 * 4));
    int*      cnt     = (int*)     (base + alloc((size_t)HB * TT * 4));
    int*      basecol = (int*)     (base + alloc((size_t)HB * TT * 4));
    int*      rank    = (int*)     (base + alloc((size_t)NN * 4));
    half2v*   x2p     = (half2v*)  (base + alloc((size_t)PADN * 96 * 4));

    hipMemsetAsync(off, 0, (size_t)(NN + 1) * 4, stream);
    hipMemsetAsync(cursor, 0, (size_t)NN * 4, stream);
    hipMemsetAsync(perm, 0xFF, (size_t)PADN * 4, stream);

    prep_pack<<<420, 256, 0, stream>>>(wih, whh, projw, wkp, projwT);
    count_indeg<<<(NE + 255) / 256, 256, 0, stream>>>(dstp, off);
    hist_rank<<<HB, 256, 0, stream>>>(ts, cnt, rank);
    scan_p1<<<SNB, 256, 0, stream>>>(off, bsum);
    scan_p2<<<1, 512, 0, stream>>>(bsum, bpre, off);
    scan_p3<<<SNB, 512, 0, stream>>>(off, bpre);
    fill_adj<<<(NE + 255) / 256, 256, 0, stream>>>(srcp, dstp, ts, off, cursor, adjsrc, tsrc);
    degf_hist<<<(NN + 255) / 256, 256, 0, stream>>>(off, tsrc, ts, dinvh, selfdeg);
    bucket_scan<<<TT, 256, 0, stream>>>(cnt, basecol, bcnt);
    make_tiles<<<1, 64, 0, stream>>>(bcnt, pstart, tile_t, tile_r0, meta);
    perm_scatter<<<HB, 256, 0, stream>>>(ts, rank, basecol, pstart, perm, pos);
    x_scatter_h<<<(NN * 96 + 255) / 256, 256, 0, stream>>>(x, pos, x2p);
    edge_compact<<<(NN + 255) / 256, 256, 0, stream>>>(off, adjsrc, tsrc, ts, dinvh, pos, ewp, nact);

    gru_evolve<<<FF, 512, 0, stream>>>(initial_w, wkp, bih, bhh, W_all);
    m_build<<<TT * 24, 1024, 0, stream>>>(W_all, projwT, Mh);

    gemm_fused4<<<MAXTILES, 512, 0, stream>>>(meta, tile_t, tile_r0, perm, selfdeg,
                                              x2p, off, nact, ewp, Mh, projb, clsw, clsb, out);
}

// Round 12
// 334.384 us; speedup vs baseline: 1.6766x; 1.1342x over previous
//
#include <hip/hip_runtime.h>
#include <hip/hip_fp16.h>
#include <math.h>

#define NN 200000
#define NE 500000
#define FF 166
#define HH 128
#define CC 2
#define TT 49
#define GG 498            // 3*FF
#define PADN 203136
#define MAXTILES 6400
#define KP 84             // k-pairs (166 -> 84 half2, padded)
#define KPAD 192          // K padded to 6*32 for MFMA
#define SCB 512           // scan elements per block
#define SNB 391           // ceil(NN/512)
#define HB 782            // ceil(NN/256) histogram blocks
#define PREPB 420         // prep_pack blocks
#define CIB 1954          // ceil(NE/256)
#define XSB 37500         // ceil(NN*48/256)

typedef _Float16 half2v __attribute__((ext_vector_type(2)));
typedef _Float16 f16x4 __attribute__((ext_vector_type(4)));
typedef _Float16 f16x8 __attribute__((ext_vector_type(8)));
typedef float f32x4 __attribute__((ext_vector_type(4)));

static __device__ __forceinline__ float fdot2f(half2v a, half2v b, float c) {
#if __has_builtin(__builtin_amdgcn_fdot2)
    return __builtin_amdgcn_fdot2(a, b, c, false);
#else
    return c + (float)a.x * (float)b.x + (float)a.y * (float)b.y;
#endif
}

// ============ setup1: prep_pack ∥ count_indeg ∥ hist_rank ============
__global__ __launch_bounds__(256) void setup1(
        const float* __restrict__ wih, const float* __restrict__ whh,
        const float* __restrict__ projw,
        _Float16* __restrict__ wkp, float* __restrict__ projwT,
        const int* __restrict__ dstp, int* __restrict__ offc,
        const int* __restrict__ ts, int* __restrict__ cnt, int* __restrict__ rank) {
    __shared__ int h[64];
    int b = blockIdx.x;
    int tid = threadIdx.x;
    if (b < PREPB) {
        int idx = b * 256 + tid;
        const int A = 2 * KP * 512;
        if (idx < A) {
            int m = idx / (KP * 512);
            int r = idx - m * (KP * 512);
            int kp = r >> 9, c = r & 511;
            const float* Wm = m ? whh : wih;
            float x0 = 0.0f, x1 = 0.0f;
            if (c < GG) {
                int k0 = 2 * kp, k1 = 2 * kp + 1;
                if (k0 < FF) x0 = Wm[c * FF + k0];
                if (k1 < FF) x1 = Wm[c * FF + k1];
            }
            wkp[2 * idx]     = (_Float16)x0;
            wkp[2 * idx + 1] = (_Float16)x1;
        } else if (idx < A + FF * HH) {
            int q = idx - A;
            int k = q >> 7, hh = q & 127;
            projwT[q] = projw[hh * FF + k];
        }
    } else if (b < PREPB + CIB) {
        int e = (b - PREPB) * 256 + tid;
        if (e < NE) atomicAdd(&offc[dstp[e]], 1);
    } else {
        int hb = b - PREPB - CIB;
        if (tid < TT) h[tid] = 0;
        __syncthreads();
        int i = hb * 256 + tid;
        if (i < NN) {
            int t = ts[i];
            rank[i] = atomicAdd(&h[t], 1);
        }
        __syncthreads();
        if (tid < TT) cnt[hb * TT + tid] = h[tid];
    }
}

// ============ setup2: scan_p1 ∥ bucket_scan ============
__global__ __launch_bounds__(256) void setup2(
        const int* __restrict__ off, int* __restrict__ bsum,
        const int* __restrict__ cnt, int* __restrict__ basecol, int* __restrict__ bcnt) {
    __shared__ int s[256];
    int b = blockIdx.x, tid = threadIdx.x;
    if (b < SNB) {
        int i0 = b * SCB + tid * 2;
        int v = 0;
        if (i0 < NN) v += off[i0];
        if (i0 + 1 < NN) v += off[i0 + 1];
        s[tid] = v;
        __syncthreads();
        for (int d = 128; d > 0; d >>= 1) {
            if (tid < d) s[tid] += s[tid + d];
            __syncthreads();
        }
        if (tid == 0) bsum[b] = s[0];
    } else {
        int t = b - SNB;
        const int CH = (HB + 255) / 256; // 4
        int b0 = tid * CH;
        int loc[4];
        int sum = 0;
        for (int u = 0; u < CH; ++u) {
            int bb = b0 + u;
            int v = (bb < HB) ? cnt[bb * TT + t] : 0;
            loc[u] = sum;
            sum += v;
        }
        s[tid] = sum;
        __syncthreads();
        for (int d = 1; d < 256; d <<= 1) {
            int u = (tid >= d) ? s[tid - d] : 0;
            __syncthreads();
            s[tid] += u;
            __syncthreads();
        }
        int base = s[tid] - sum;
        for (int u = 0; u < CH; ++u) {
            int bb = b0 + u;
            if (bb < HB) basecol[bb * TT + t] = base + loc[u];
        }
        if (tid == 255) bcnt[t] = s[255];
    }
}

// ============ setup3: scan_p2 (block 0) ∥ make_tiles (block 1) ============
__global__ __launch_bounds__(512) void setup3(
        const int* __restrict__ bsum, int* __restrict__ bpre, int* __restrict__ off,
        const int* __restrict__ bcnt, int* __restrict__ pstart,
        int* __restrict__ tile_t, int* __restrict__ tile_r0, int* __restrict__ meta) {
    __shared__ int s[512];
    int tid = threadIdx.x;
    if (blockIdx.x == 0) {
        int v = (tid < SNB) ? bsum[tid] : 0;
        s[tid] = v;
        __syncthreads();
        for (int d = 1; d < 512; d <<= 1) {
            int u = (tid >= d) ? s[tid - d] : 0;
            __syncthreads();
            s[tid] += u;
            __syncthreads();
        }
        bpre[tid] = s[tid] - v;
        if (tid == 511) off[NN] = s[511];
    } else {
        int t = tid;
        int nt = (t < TT) ? (bcnt[t] + 31) / 32 : 0;
        if (t < 64) s[t] = nt;
        __syncthreads();
        for (int d = 1; d < 64; d <<= 1) {
            int v = (t >= d && t < 64) ? s[t - d] : 0;
            __syncthreads();
            if (t < 64) s[t] += v;
            __syncthreads();
        }
        if (t < 64) {
            int ntbase = s[t] - nt;
            int pbase = ntbase * 32;
            if (t < TT) {
                pstart[t] = pbase;
                for (int u = 0; u < nt; ++u) {
                    tile_t[ntbase + u] = t;
                    tile_r0[ntbase + u] = pbase + u * 32;
                }
            }
            if (t == 63) {
                meta[0] = s[63];
                meta[1] = s[63] * 32;
                pstart[TT] = s[63] * 32;
            }
        }
    }
}

// ============ setup4: scan_p3 ∥ perm_scatter ============
__global__ __launch_bounds__(512) void setup4(
        int* __restrict__ off, const int* __restrict__ bpre,
        const int* __restrict__ ts, const int* __restrict__ rank,
        const int* __restrict__ basecol, const int* __restrict__ pstart,
        int* __restrict__ perm, int* __restrict__ pos) {
    __shared__ int s[512];
    int b = blockIdx.x, tid = threadIdx.x;
    if (b < SNB) {
        int i = b * SCB + tid;
        int v = (i < NN) ? off[i] : 0;
        s[tid] = v;
        __syncthreads();
        for (int d = 1; d < 512; d <<= 1) {
            int u = (tid >= d) ? s[tid - d] : 0;
            __syncthreads();
            s[tid] += u;
            __syncthreads();
        }
        if (i < NN) off[i] = s[tid] - v + bpre[b];
    } else {
        int i = (b - SNB) * 512 + tid;
        if (i < NN) {
            int t = ts[i];
            int hb = i >> 8;
            int p = pstart[t] + basecol[hb * TT + t] + rank[i];
            perm[p] = i;
            pos[i] = p;
        }
    }
}

// ============ setup5: fill_adj ∥ x_scatter (fp16, perm order, f16x4 cells) ============
__global__ __launch_bounds__(256) void setup5(
        const int* __restrict__ srcp, const int* __restrict__ dstp,
        const int* __restrict__ ts, const int* __restrict__ off,
        int* __restrict__ cursor, int2* __restrict__ adjst,
        const float* __restrict__ x, const int* __restrict__ pos,
        f16x4* __restrict__ x2p4) {
    int b = blockIdx.x, tid = threadIdx.x;
    if (b < CIB) {
        int e = b * 256 + tid;
        if (e < NE) {
            int d = dstp[e];
            int s2 = srcp[e];
            int p = atomicAdd(&cursor[d], 1);
            adjst[off[d] + p] = make_int2(s2, ts[s2]);
        }
    } else {
        int idx = (b - CIB) * 256 + tid;
        if (idx >= NN * 48) return;
        int i = idx / 48, cp4 = idx - i * 48;
        int c0 = cp4 * 4;
        float v0 = 0.f, v1 = 0.f, v2 = 0.f, v3 = 0.f;
        const float* xr = x + (size_t)i * FF;
        if (c0 + 3 < FF) {
            float2 p0 = *(const float2*)(xr + c0);
            float2 p1 = *(const float2*)(xr + c0 + 2);
            v0 = p0.x; v1 = p0.y; v2 = p1.x; v3 = p1.y;
        } else if (c0 < FF) {   // c0 == 164
            float2 p0 = *(const float2*)(xr + c0);
            v0 = p0.x; v1 = p0.y;
        }
        f16x4 h;
        h[0] = (_Float16)v0; h[1] = (_Float16)v1;
        h[2] = (_Float16)v2; h[3] = (_Float16)v3;
        x2p4[(size_t)pos[i] * 48 + cp4] = h;
    }
}

// ============ degf_hist: dinvh[t][i], selfdeg[i] ============
__global__ __launch_bounds__(256) void degf_hist(const int* __restrict__ off, const int2* __restrict__ adjst,
                                                 const int* __restrict__ ts, _Float16* __restrict__ dinvh,
                                                 float* __restrict__ selfdeg) {
    __shared__ unsigned short sh[TT * 256];
    int tid = threadIdx.x;
    int i = blockIdx.x * 256 + tid;
    for (int t = 0; t < TT; ++t) sh[t * 256 + tid] = 0;
    if (i >= NN) return;
    int tsi = ts[i];
    int e0 = off[i], e1 = off[i + 1];
    for (int e = e0; e < e1; ++e) {
        int tj = adjst[e].y;
        sh[tj * 256 + tid]++;
    }
    int cum = 1;
    for (int t = 0; t < TT; ++t) {
        cum += sh[t * 256 + tid];
        dinvh[(size_t)t * NN + i] = (_Float16)rsqrtf((float)cum);
        if (t == tsi) selfdeg[i] = 1.0f / (float)cum;
    }
}

// ============ edge_compact: ewp[off[i]..] = {pos[j], w>0} ============
__global__ __launch_bounds__(256) void edge_compact(
        const int* __restrict__ off, const int2* __restrict__ adjst,
        const int* __restrict__ ts, const _Float16* __restrict__ dinvh, const int* __restrict__ pos,
        int2* __restrict__ ewp, int* __restrict__ nact) {
    int i = blockIdx.x * 256 + threadIdx.x;
    if (i >= NN) return;
    int t = ts[i];
    const _Float16* dv = dinvh + (size_t)t * NN;
    float dvi = (float)dv[i];
    int e0 = off[i], e1 = off[i + 1];
    int c = e0;
    for (int e = e0; e < e1; ++e) {
        int2 a = adjst[e];
        if (a.y <= t) {
            float w = (float)dv[a.x] * dvi;
            ewp[c++] = make_int2(pos[a.x], __float_as_int(w));
        }
    }
    nact[i] = c - e0;
}

// ============ GRU chain: 1 row/block, weights register-resident ============
__global__ __launch_bounds__(512) void gru_evolve(
        const float* __restrict__ initial_w,
        const _Float16* __restrict__ wkp,
        const float* __restrict__ bih, const float* __restrict__ bhh,
        float* __restrict__ W_all) {
    __shared__ float s_w[FF];
    __shared__ __align__(16) _Float16 s_wh[2 * KP];
    __shared__ float s_pre[2][512];
    int tid = threadIdx.x;
    int row = blockIdx.x;

    if (tid < FF) {
        float v = initial_w[(size_t)row * FF + tid];
        s_w[tid] = v;
        s_wh[tid] = (_Float16)v;
    } else if (tid < 2 * KP) {
        s_wh[tid] = (_Float16)0.0f;
    }

    int cc0 = tid * 2;
    bool act = cc0 < 996;
    int m = (cc0 >= 498) ? 1 : 0;
    int c0 = act ? (cc0 - m * 498) : 0;

    half2v wr0[KP], wr1[KP];
    {
        const half2v* __restrict__ pW =
            (const half2v*)wkp + (size_t)(act ? m : 0) * (KP * 512) + c0;
        #pragma unroll
        for (int kp = 0; kp < KP; ++kp) {
            wr0[kp] = pW[(size_t)(kp << 9)];
            wr1[kp] = pW[(size_t)(kp << 9) + 1];
        }
    }

    float bi_r = 0, bi_z = 0, bi_n = 0, bh_r = 0, bh_z = 0, bh_n = 0;
    if (tid < FF) {
        bi_r = bih[tid]; bi_z = bih[FF + tid]; bi_n = bih[2 * FF + tid];
        bh_r = bhh[tid]; bh_z = bhh[FF + tid]; bh_n = bhh[2 * FF + tid];
    }
    __syncthreads();

    const f16x8* s_wh8 = (const f16x8*)s_wh;
    for (int t = 0; t < TT; ++t) {
        if (act) {
            float a0 = 0.0f, a1 = 0.0f;
            #pragma unroll
            for (int q = 0; q < 21; ++q) {
                f16x8 w8 = s_wh8[q];
                half2v h0 = __builtin_shufflevector(w8, w8, 0, 1);
                half2v h1 = __builtin_shufflevector(w8, w8, 2, 3);
                half2v h2 = __builtin_shufflevector(w8, w8, 4, 5);
                half2v h3 = __builtin_shufflevector(w8, w8, 6, 7);
                a0 = fdot2f(wr0[4 * q + 0], h0, a0);  a1 = fdot2f(wr1[4 * q + 0], h0, a1);
                a0 = fdot2f(wr0[4 * q + 1], h1, a0);  a1 = fdot2f(wr1[4 * q + 1], h1, a1);
                a0 = fdot2f(wr0[4 * q + 2], h2, a0);  a1 = fdot2f(wr1[4 * q + 2], h2, a1);
                a0 = fdot2f(wr0[4 * q + 3], h3, a0);  a1 = fdot2f(wr1[4 * q + 3], h3, a1);
            }
            s_pre[m][c0]     = a0;
            s_pre[m][c0 + 1] = a1;
        }
        __syncthreads();
        if (tid < FF) {
            float i_r = s_pre[0][tid]          + bi_r;
            float h_r = s_pre[1][tid]          + bh_r;
            float i_z = s_pre[0][FF + tid]     + bi_z;
            float h_z = s_pre[1][FF + tid]     + bh_z;
            float i_n = s_pre[0][2 * FF + tid] + bi_n;
            float h_n = s_pre[1][2 * FF + tid] + bh_n;
            float rg = 1.0f / (1.0f + expf(-(i_r + h_r)));
            float zg = 1.0f / (1.0f + expf(-(i_z + h_z)));
            float ng = tanhf(i_n + rg * h_n);
            float wnew = (1.0f - zg) * ng + zg * s_w[tid];
            s_w[tid] = wnew;
            s_wh[tid] = (_Float16)wnew;
            W_all[((size_t)t * FF + row) * FF + tid] = wnew;
        }
        __syncthreads();
    }
}

// ============ Mh[t][h][k] (fp16, k padded to 192) ============
__global__ __launch_bounds__(1024) void m_build(const float* __restrict__ W_all,
                                                const float* __restrict__ projwT,
                                                _Float16* __restrict__ Mh) {
    __shared__ __align__(16) float sw[8][168];
    int blk = blockIdx.x;
    int t = blk / 24, rb = blk - t * 24;
    int tid = threadIdx.x;
    int r0 = rb * 8;
    for (int idx = tid; idx < 8 * FF; idx += 1024) {
        int rr = idx / FF, k = idx - rr * FF;
        int r = r0 + rr;
        sw[rr][k] = (r < FF) ? W_all[((size_t)t * FF + r) * FF + k] : 0.0f;
    }
    __syncthreads();
    int rr = tid >> 7, h = tid & 127;
    int r = r0 + rr;
    if (r >= KPAD) return;
    float acc = 0.0f;
    if (r < FF) {
        const float* __restrict__ pw = projwT + h;
        #pragma unroll 4
        for (int c4 = 0; c4 < 164; c4 += 4) {
            float4 w = *(const float4*)&sw[rr][c4];
            acc += w.x * pw[(size_t)(c4 + 0) << 7];
            acc += w.y * pw[(size_t)(c4 + 1) << 7];
            acc += w.z * pw[(size_t)(c4 + 2) << 7];
            acc += w.w * pw[(size_t)(c4 + 3) << 7];
        }
        acc += sw[rr][164] * pw[(size_t)164 << 7];
        acc += sw[rr][165] * pw[(size_t)165 << 7];
    }
    Mh[((size_t)t * HH + h) * KPAD + r] = (_Float16)acc;
}

// ============ fused: staged self + pipelined 8B-lane edge gather + MFMA + proj + cls ============
__global__ __launch_bounds__(512) void gemm_fused5(
        const int* __restrict__ meta, const int* __restrict__ tile_t,
        const int* __restrict__ tile_r0, const int* __restrict__ perm,
        const float* __restrict__ selfdeg, const f16x4* __restrict__ x2p4,
        const int* __restrict__ off, const int* __restrict__ nact,
        const int2* __restrict__ ewp,
        const _Float16* __restrict__ Mh, const float* __restrict__ proj_b,
        const float* __restrict__ cls_w, const float* __restrict__ cls_b,
        float* __restrict__ out) {
    __shared__ __align__(16) char smraw[32 * 130 * 4];
    _Float16* sY = (_Float16*)smraw;   // [32][200] fp16
    float* sP = (float*)smraw;         // [32][130] f32
    int bid = blockIdx.x;
    if (bid >= meta[0]) return;
    int t = tile_t[bid], r0 = tile_r0[bid];
    int tid = threadIdx.x;
    int lane = tid & 63;
    int w = tid >> 6;          // 8 waves
    bool ln48 = lane < 48;

    // ---- stage x2p tile (32 contiguous rows x 24 uint4 = 12 KB) ----
    {
        const uint4* src = (const uint4*)(x2p4 + (size_t)r0 * 48);
        #pragma unroll
        for (int u = 0; u < 2; ++u) {
            int q = tid + u * 512;
            if (q < 768) {
                int row = q / 24, kc = q - row * 24;
                *(uint4*)(sY + row * 200 + kc * 8) = src[q];
            }
        }
    }
    __syncthreads();

    // ---- phase 0: per-wave 4-row aggregation, 8B/lane, pipelined ewp ----
    int rbase = w * 4;
    int ep[4], ee[4];
    float ac[4][4];
    #pragma unroll
    for (int q = 0; q < 4; ++q) {
        int r = rbase + q;
        int i = perm[r0 + r];
        float sw = 0.0f;
        ep[q] = 0; ee[q] = 0;
        if (i >= 0) {
            sw = selfdeg[i];
            ep[q] = off[i];
            ee[q] = ep[q] + nact[i];
        }
        f16x4 h = (f16x4)((_Float16)0.0f);
        if (ln48) h = *(const f16x4*)(sY + r * 200 + lane * 4);
        ac[q][0] = sw * (float)h[0];
        ac[q][1] = sw * (float)h[1];
        ac[q][2] = sw * (float)h[2];
        ac[q][3] = sw * (float)h[3];
    }
    int2 pc[4];
    #pragma unroll
    for (int q = 0; q < 4; ++q) pc[q] = (ep[q] < ee[q]) ? ewp[ep[q]] : make_int2(0, 0);
    while ((ep[0] < ee[0]) | (ep[1] < ee[1]) | (ep[2] < ee[2]) | (ep[3] < ee[3])) {
        int js[4]; float wv[4];
        #pragma unroll
        for (int q = 0; q < 4; ++q) {
            bool val = ep[q] < ee[q];
            js[q] = pc[q].x;
            wv[q] = val ? __int_as_float(pc[q].y) : 0.0f;
            if (val) ep[q]++;
        }
        #pragma unroll
        for (int q = 0; q < 4; ++q) pc[q] = (ep[q] < ee[q]) ? ewp[ep[q]] : make_int2(0, 0);
        #pragma unroll
        for (int q = 0; q < 4; ++q) {
            if (wv[q] != 0.0f && ln48) {
                f16x4 g = x2p4[(size_t)js[q] * 48 + lane];
                ac[q][0] += wv[q] * (float)g[0];
                ac[q][1] += wv[q] * (float)g[1];
                ac[q][2] += wv[q] * (float)g[2];
                ac[q][3] += wv[q] * (float)g[3];
            }
        }
    }
    // each wave overwrites only its own rows (no cross-wave hazard before this point)
    #pragma unroll
    for (int q = 0; q < 4; ++q) {
        if (ln48) {
            f16x4 o;
            o[0] = (_Float16)ac[q][0];
            o[1] = (_Float16)ac[q][1];
            o[2] = (_Float16)ac[q][2];
            o[3] = (_Float16)ac[q][3];
            *(f16x4*)(sY + (rbase + q) * 200 + lane * 4) = o;
        }
    }
    __syncthreads();

    // ---- phase 1: MFMA. wave w -> 16-col block c0 = w*16
    int lr = lane & 15;
    int kg = lane >> 4;
    int c0 = w * 16;
    f32x4 acc0 = {0, 0, 0, 0}, acc1 = {0, 0, 0, 0};
    const _Float16* B0 = Mh + ((size_t)t * HH + c0 + lr) * KPAD + kg * 8;
    const _Float16* A0 = sY + lr * 200 + kg * 8;
    const _Float16* A1 = A0 + 16 * 200;

    #pragma unroll
    for (int s = 0; s < 6; ++s) {
        f16x8 b0 = *(const f16x8*)(B0 + s * 32);
        f16x8 a0 = *(const f16x8*)(A0 + s * 32);
        f16x8 a1 = *(const f16x8*)(A1 + s * 32);
        acc0 = __builtin_amdgcn_mfma_f32_16x16x32_f16(a0, b0, acc0, 0, 0, 0);
        acc1 = __builtin_amdgcn_mfma_f32_16x16x32_f16(a1, b0, acc1, 0, 0, 0);
    }

    float pb = proj_b[c0 + lr];
    __syncthreads();
    int prow = kg * 4;
    int colw = c0 + lr;
    #pragma unroll
    for (int r = 0; r < 4; ++r) {
        sP[(prow + r) * 130 + colw]      = fmaxf(acc0[r] + pb, 0.0f);
        sP[(16 + prow + r) * 130 + colw] = fmaxf(acc1[r] + pb, 0.0f);
    }
    __syncthreads();

    // ---- phase 2: logits
    int row = tid >> 4, cc = (tid >> 3) & 1, qq = tid & 7;
    const float* pr = sP + row * 130 + qq * 16;
    const float* cw = cls_w + cc * HH + qq * 16;
    float s = 0.0f;
    #pragma unroll
    for (int h = 0; h < 16; ++h) s += pr[h] * cw[h];
    s += __shfl_xor(s, 1);
    s += __shfl_xor(s, 2);
    s += __shfl_xor(s, 4);
    if (qq == 0) {
        int node = perm[r0 + row];
        if (node >= 0) out[(size_t)node * CC + cc] = s + cls_b[cc];
    }
}

// ============ host ============
extern "C" void kernel_launch(void* const* d_in, const int* in_sizes, int n_in,
                              void* d_out, int out_size, void* d_ws, size_t ws_size,
                              hipStream_t stream) {
    const float* x = (const float*)d_in[0];
    const int* ei = (const int*)d_in[1];
    const int* srcp = ei;
    const int* dstp = ei + NE;
    const int* ts = (const int*)d_in[2];
    const float* initial_w = (const float*)d_in[3];
    const float* wih = (const float*)d_in[4];
    const float* whh = (const float*)d_in[5];
    const float* bih = (const float*)d_in[6];
    const float* bhh = (const float*)d_in[7];
    const float* projw = (const float*)d_in[8];
    const float* projb = (const float*)d_in[9];
    const float* clsw = (const float*)d_in[10];
    const float* clsb = (const float*)d_in[11];
    float* out = (float*)d_out;

    char* base = (char*)d_ws;
    size_t o = 0;
    auto alloc = [&](size_t bytes) { size_t r = o; o = (o + bytes + 255) & ~(size_t)255; return r; };

    float*    W_all   = (float*)   (base + alloc((size_t)TT * FF * FF * 4));
    _Float16* Mh      = (_Float16*)(base + alloc((size_t)TT * HH * KPAD * 2));
    _Float16* wkp     = (_Float16*)(base + alloc((size_t)2 * KP * 512 * 2 * 2));
    float*    projwT  = (float*)   (base + alloc((size_t)FF * HH * 4));
    int*      off     = (int*)     (base + alloc((size_t)(NN + 1) * 4));
    int*      cursor  = (int*)     (base + alloc((size_t)NN * 4));
    int2*     adjst   = (int2*)    (base + alloc((size_t)NE * 8));
    int2*     ewp     = (int2*)    (base + alloc((size_t)NE * 8));
    _Float16* dinvh   = (_Float16*)(base + alloc((size_t)TT * NN * 2));
    float*    selfdeg = (float*)   (base + alloc((size_t)NN * 4));
    int*      nact    = (int*)     (base + alloc((size_t)NN * 4));
    int*      pos     = (int*)     (base + alloc((size_t)NN * 4));
    int*      bcnt    = (int*)     (base + alloc((size_t)TT * 4));
    int*      pstart  = (int*)     (base + alloc((size_t)(TT + 1) * 4));
    int*      meta    = (int*)     (base + alloc(2 * 4));
    int*      tile_t  = (int*)     (base + alloc((size_t)MAXTILES * 4));
    int*      tile_r0 = (int*)     (base + alloc((size_t)MAXTILES * 4));
    int*      perm    = (int*)     (base + alloc((size_t)PADN * 4));
    int*      bsum    = (int*)     (base + alloc((size_t)512 * 4));
    int*      bpre    = (int*)     (base + alloc((size_t)520 * 4));
    int*      cnt     = (int*)     (base + alloc((size_t)HB * TT * 4));
    int*      basecol = (int*)     (base + alloc((size_t)HB * TT * 4));
    int*      rank    = (int*)     (base + alloc((size_t)NN * 4));
    f16x4*    x2p4    = (f16x4*)   (base + alloc((size_t)PADN * 48 * 8));

    // off and cursor are adjacent: one memset covers both
    hipMemsetAsync(off, 0, (size_t)((char*)cursor - (char*)off) + (size_t)NN * 4, stream);
    hipMemsetAsync(perm, 0xFF, (size_t)PADN * 4, stream);

    setup1<<<PREPB + CIB + HB, 256, 0, stream>>>(wih, whh, projw, wkp, projwT,
                                                 dstp, off, ts, cnt, rank);
    setup2<<<SNB + TT, 256, 0, stream>>>(off, bsum, cnt, basecol, bcnt);
    setup3<<<2, 512, 0, stream>>>(bsum, bpre, off, bcnt, pstart, tile_t, tile_r0, meta);
    setup4<<<SNB + SNB, 512, 0, stream>>>(off, bpre, ts, rank, basecol, pstart, perm, pos);
    setup5<<<CIB + XSB, 256, 0, stream>>>(srcp, dstp, ts, off, cursor, adjst, x, pos, x2p4);
    degf_hist<<<(NN + 255) / 256, 256, 0, stream>>>(off, adjst, ts, dinvh, selfdeg);
    edge_compact<<<(NN + 255) / 256, 256, 0, stream>>>(off, adjst, ts, dinvh, pos, ewp, nact);

    gru_evolve<<<FF, 512, 0, stream>>>(initial_w, wkp, bih, bhh, W_all);
    m_build<<<TT * 24, 1024, 0, stream>>>(W_all, projwT, Mh);

    gemm_fused5<<<MAXTILES, 512, 0, stream>>>(meta, tile_t, tile_r0, perm, selfdeg,
                                              x2p4, off, nact, ewp, Mh, projb, clsw, clsb, out);
}